// Round 7
// baseline (521.920 us; speedup 1.0000x reference)
//
#include <hip/hip_runtime.h>
#include <hip/hip_bf16.h>
#include <cstdint>

typedef short short8 __attribute__((ext_vector_type(8)));
typedef float floatx4 __attribute__((ext_vector_type(4)));
typedef float f32x4 __attribute__((ext_vector_type(4)));
typedef unsigned short u16;
typedef unsigned short u16x4 __attribute__((ext_vector_type(4)));

#define BB 8192
#define DD 2048
#define HH 4096

static __device__ __forceinline__ u16 f2bf(float x) {
  __hip_bfloat16 h = __float2bfloat16(x);
  return __builtin_bit_cast(u16, h);
}

static __device__ __forceinline__ void glds16(const u16* g, u16* l) {
  __builtin_amdgcn_global_load_lds(
      (const __attribute__((address_space(1))) void*)g,
      (__attribute__((address_space(3))) void*)l, 16, 0, 0);
}

// ---------------- elementwise: value fp32 -> bf16 ----------------
__global__ void cvt_value_kernel(const float* __restrict__ in, u16* __restrict__ out, int n4) {
  int idx = blockIdx.x * blockDim.x + threadIdx.x;
  int stride = gridDim.x * blockDim.x;
  for (int i = idx; i < n4; i += stride) {
    f32x4 v = reinterpret_cast<const f32x4*>(in)[i];
    u16x4 o = { f2bf(v[0]), f2bf(v[1]), f2bf(v[2]), f2bf(v[3]) };
    reinterpret_cast<u16x4*>(out)[i] = o;
  }
}

// ---------------- mask + cast weights ----------------
// MODE 0: W1 (H x D),  keep col <= row%2047
// MODE 1: W2 (H x H),  keep col%2047 <= row%2047
// MODE 2: W3 (D x H),  keep row > col%2047
template<int MODE>
__global__ void mask_cvt_kernel(const float* __restrict__ in, u16* __restrict__ out, int n4) {
  const int shift = (MODE == 0) ? 11 : 12;
  const int cmask = (MODE == 0) ? 2047 : 4095;
  int idx0 = blockIdx.x * blockDim.x + threadIdx.x;
  int stride = gridDim.x * blockDim.x;
  for (int i = idx0; i < n4; i += stride) {
    int e0 = i * 4;
    int row = e0 >> shift;
    int col = e0 & cmask;
    int rdeg = row % 2047;
    f32x4 v = reinterpret_cast<const f32x4*>(in)[i];
    u16x4 o;
#pragma unroll
    for (int e = 0; e < 4; ++e) {
      int c = col + e;
      bool keep;
      if (MODE == 0)      keep = (c <= rdeg);
      else if (MODE == 1) keep = ((c % 2047) <= rdeg);
      else                keep = (row > (c % 2047));
      o[e] = keep ? f2bf(v[e]) : (u16)0;
    }
    reinterpret_cast<u16x4*>(out)[i] = o;
  }
}

// ---------------- GEMM: C(MxN) = A(MxK) * Bw(NxK)^T, bf16 MFMA ----------------
// Pipelined double-buffered LDS (BK=32, slot = i&1) with COUNTED vmcnt and
// raw s_barrier (no vmcnt(0) drain in steady state):
//   iter i: STAGE(tile i+1 -> slot^1); vmcnt(NG) [tile i landed, i+1 in
//   flight]; s_barrier; ds_read+MFMA slot; lgkmcnt(0); s_barrier.
// Needed K-blocks form two dense runs [0,r1end) U [run2start,r2end) (exact:
// boundary blocks multiply stored zeros), so prefetch addresses are linear.
// LDS rows XOR-swizzled: ssub = sub ^ ((row^(row>>2))&3), applied on the
// pre-swizzled GLOBAL source (glds dest stays linear) and on the read addr;
// residual conflicts are 2-way (free).
//
// EPI 0: C = relu(acc + bias); EPI 1: logprob reduce -> atomicAdd(outp)
// MASK 1: W1-triangular; MASK 2: W2 two-segment; MASK 3: W3 two-segment
// WORK BALANCE: block processes column-tile PAIR {q, 15-q} (equal work/block).
template<int EPI, int MASK, int BM>
__global__ __launch_bounds__(256) void gemm_kernel(
    const u16* __restrict__ A,
    const u16* __restrict__ Bw,
    const float* __restrict__ bias,
    u16* __restrict__ C,
    const float* __restrict__ value,
    float* __restrict__ outp,
    int M, int N, int K)
{
  constexpr int MI    = BM / 32;     // acc fragments per wave in M
  constexpr int AU    = BM / 64;     // A glds per thread per tile
  constexpr int NG    = AU + 2;      // total glds per thread per tile
  constexpr int ATILE = BM * 32;     // elems per A tile
  constexpr int BTILE = 128 * 32;
  __shared__ u16 lsA[2 * ATILE];
  __shared__ u16 lsB[2 * BTILE];

  const int tid  = threadIdx.x;
  const int wave = tid >> 6;
  const int lane = tid & 63;
  const int wr = wave >> 1;     // 2x2 wave grid; wave tile = (BM/2) x 64
  const int wc = wave & 1;
  const int l15 = lane & 15;
  const int lhi = lane >> 4;
  const int brow = blockIdx.y * BM;

  // balanced column-tile pair for this block
  const int p = blockIdx.x;
  int cols[2];
  if (gridDim.x == 16) {                 // 32-column GEMMs (G1, G2)
    cols[0] = (p < 8) ? p : p + 8;
    cols[1] = (p < 8) ? 15 - p : 39 - p;
  } else {                               // 16-column GEMM (G3)
    cols[0] = p;
    cols[1] = 15 - p;
  }

  // staging descriptors: 16B chunks, 4 per row (BK=32); pre-swizzled source
  int aCh[AU]; size_t aOff[AU];
#pragma unroll
  for (int u = 0; u < AU; ++u) {
    int ch = tid + 256 * u;
    int row = ch >> 2, sub = ch & 3;
    int ssub = sub ^ ((row ^ (row >> 2)) & 3);
    aCh[u] = ch;
    aOff[u] = (size_t)(brow + row) * K + ssub * 8;
  }
  int bCh[2], bRow[2], bSsub[2];
#pragma unroll
  for (int u = 0; u < 2; ++u) {
    int ch = tid + 256 * u;
    int row = ch >> 2, sub = ch & 3;
    bCh[u] = ch;
    bRow[u] = row;
    bSsub[u] = sub ^ ((row ^ (row >> 2)) & 3);
  }

#pragma unroll
  for (int t = 0; t < 2; ++t) {
    const int bcol = cols[t] * 128;

    // max needed hidden-degree index over this column tile (wave-uniform)
    int rmax;
    {
      int s = bcol, e = bcol + 127;
      if (MASK == 3) {
        rmax = bcol + 126;
      } else {
        if (e <= 2046)      rmax = e;
        else if (s <= 2046) rmax = 2046;
        else {
          int em = e - 2047;
          rmax = (em <= 2046) ? em : 2046;
        }
      }
    }

    // two dense K-runs covering all needed BK=32 blocks
    int r1end = ((rmax >> 5) + 1) << 5; if (r1end > K) r1end = K;
    int run2start, r2end;
    if (MASK == 1) {
      run2start = r1end; r2end = r1end;            // empty run2
    } else {
      run2start = (2016 > r1end) ? 2016 : r1end;   // first block touching k=2047
      r2end = (((2047 + rmax) >> 5) + 1) << 5; if (r2end > K) r2end = K;
      if (r2end < run2start) r2end = run2start;
    }
    const int n1 = r1end >> 5;
    const int nt = n1 + ((r2end - run2start) >> 5);
    const int roff = run2start - r1end;            // K0(i) = i*32 + (i>=n1)*roff

    size_t bOff[2];
#pragma unroll
    for (int u = 0; u < 2; ++u)
      bOff[u] = (size_t)(bcol + bRow[u]) * K + bSsub[u] * 8;

    floatx4 acc[MI][4];
#pragma unroll
    for (int i = 0; i < MI; ++i)
#pragma unroll
      for (int j = 0; j < 4; ++j)
        acc[i][j] = (floatx4){0.f, 0.f, 0.f, 0.f};

    // prologue: stage tile 0 (k0 = 0) into slot 0
#pragma unroll
    for (int u = 0; u < AU; ++u) glds16(A + aOff[u], &lsA[aCh[u] * 8]);
#pragma unroll
    for (int u = 0; u < 2;  ++u) glds16(Bw + bOff[u], &lsB[bCh[u] * 8]);

    for (int i = 0; i < nt; ++i) {
      const int slot = i & 1;
      if (i + 1 < nt) {
        const int k1 = ((i + 1) << 5) + ((i + 1 >= n1) ? roff : 0);
        const int so = slot ^ 1;
#pragma unroll
        for (int u = 0; u < AU; ++u) glds16(A + aOff[u] + k1, &lsA[so * ATILE + aCh[u] * 8]);
#pragma unroll
        for (int u = 0; u < 2;  ++u) glds16(Bw + bOff[u] + k1, &lsB[so * BTILE + bCh[u] * 8]);
        asm volatile("s_waitcnt vmcnt(%0)" :: "i"(NG) : "memory");
      } else {
        asm volatile("s_waitcnt vmcnt(0)" ::: "memory");
      }
      __builtin_amdgcn_sched_barrier(0);
      __builtin_amdgcn_s_barrier();          // tile i fully in LDS (all waves)
      __builtin_amdgcn_sched_barrier(0);

      const u16* cA = &lsA[slot * ATILE];
      const u16* cB = &lsB[slot * BTILE];
      short8 af[MI], bfv[4];
#pragma unroll
      for (int mi = 0; mi < MI; ++mi) {
        int row = wr * (BM / 2) + mi * 16 + l15;
        af[mi] = *(const short8*)&cA[row * 32 + ((lhi ^ ((row ^ (row >> 2)) & 3)) * 8)];
      }
#pragma unroll
      for (int ni = 0; ni < 4; ++ni) {
        int row = wc * 64 + ni * 16 + l15;
        bfv[ni] = *(const short8*)&cB[row * 32 + ((lhi ^ ((row ^ (row >> 2)) & 3)) * 8)];
      }
#pragma unroll
      for (int mi = 0; mi < MI; ++mi)
#pragma unroll
        for (int ni = 0; ni < 4; ++ni)
          acc[mi][ni] = __builtin_amdgcn_mfma_f32_16x16x32_bf16(af[mi], bfv[ni], acc[mi][ni], 0, 0, 0);

      asm volatile("s_waitcnt lgkmcnt(0)" ::: "memory");
      __builtin_amdgcn_sched_barrier(0);
      __builtin_amdgcn_s_barrier();          // slot reads done; safe to overwrite next iter
    }

    if (EPI == 0) {
#pragma unroll
      for (int mi = 0; mi < MI; ++mi) {
        int row = brow + wr * (BM / 2) + mi * 16 + lhi * 4;
#pragma unroll
        for (int ni = 0; ni < 4; ++ni) {
          int col = bcol + wc * 64 + ni * 16 + l15;
          float bv = bias[col];
#pragma unroll
          for (int e = 0; e < 4; ++e) {
            float v = acc[mi][ni][e] + bv;
            v = fmaxf(v, 0.0f);
            C[(size_t)(row + e) * N + col] = f2bf(v);
          }
        }
      }
    } else {
#pragma unroll
      for (int mi = 0; mi < MI; ++mi) {
#pragma unroll
        for (int e = 0; e < 4; ++e) {
          int row = brow + wr * (BM / 2) + mi * 16 + lhi * 4 + e;
          float partial = 0.0f;
#pragma unroll
          for (int ni = 0; ni < 4; ++ni) {
            int col = bcol + wc * 64 + ni * 16 + l15;
            float l = acc[mi][ni][e] + bias[col];
            float v = value[(size_t)row * N + col];
            float sp = fmaxf(l, 0.0f) + __logf(1.0f + __expf(-fabsf(l)));
            partial += v * l - sp;
          }
#pragma unroll
          for (int off = 1; off < 16; off <<= 1)
            partial += __shfl_xor(partial, off, 64);
          if (l15 == 0) atomicAdd(&outp[row], partial);
        }
      }
    }
  }
}

// ---------------- launcher ----------------
extern "C" void kernel_launch(void* const* d_in, const int* in_sizes, int n_in,
                              void* d_out, int out_size, void* d_ws, size_t ws_size,
                              hipStream_t stream) {
  const float* value = (const float*)d_in[0];
  const float* W1 = (const float*)d_in[1];
  const float* b1 = (const float*)d_in[2];
  const float* W2 = (const float*)d_in[3];
  const float* b2 = (const float*)d_in[4];
  const float* W3 = (const float*)d_in[5];
  const float* b3 = (const float*)d_in[6];
  float* out = (float*)d_out;

  char* ws = (char*)d_ws;
  u16* vbf = (u16*)(ws);                        // B*D bf16
  u16* w1m = (u16*)(ws + 33554432ULL);          // H*D bf16
  u16* w2m = (u16*)(ws + 50331648ULL);          // H*H bf16
  u16* w3m = (u16*)(ws + 83886080ULL);          // D*H bf16
  u16* h1  = (u16*)(ws + 100663296ULL);         // B*H bf16
  u16* h2  = (u16*)(ws + 167772160ULL);         // B*H bf16

  hipMemsetAsync(d_out, 0, (size_t)out_size * sizeof(float), stream);

  cvt_value_kernel<<<2048, 256, 0, stream>>>(value, vbf, (BB * DD) / 4);
  mask_cvt_kernel<0><<<2048, 256, 0, stream>>>(W1, w1m, (HH * DD) / 4);
  mask_cvt_kernel<1><<<2048, 256, 0, stream>>>(W2, w2m, (HH * HH) / 4);
  mask_cvt_kernel<2><<<2048, 256, 0, stream>>>(W3, w3m, (DD * HH) / 4);

  dim3 g12(16, BB / 128);
  gemm_kernel<0, 1, 128><<<g12, 256, 0, stream>>>(vbf, w1m, b1, h1, nullptr, nullptr, BB, HH, DD);
  gemm_kernel<0, 2, 128><<<g12, 256, 0, stream>>>(h1, w2m, b2, h2, nullptr, nullptr, BB, HH, HH);
  dim3 g3(8, BB / 64);
  gemm_kernel<1, 3, 64><<<g3, 256, 0, stream>>>(h2, w3m, b3, nullptr, value, out, BB, DD, HH);
}

// Round 8
// 449.046 us; speedup vs baseline: 1.1623x; 1.1623x over previous
//
#include <hip/hip_runtime.h>
#include <hip/hip_bf16.h>
#include <cstdint>

typedef short short8 __attribute__((ext_vector_type(8)));
typedef float floatx4 __attribute__((ext_vector_type(4)));
typedef float f32x4 __attribute__((ext_vector_type(4)));
typedef unsigned short u16;
typedef unsigned short u16x4 __attribute__((ext_vector_type(4)));

#define BB 8192
#define DD 2048
#define HH 4096

static __device__ __forceinline__ u16 f2bf(float x) {
  __hip_bfloat16 h = __float2bfloat16(x);
  return __builtin_bit_cast(u16, h);
}

static __device__ __forceinline__ void glds16(const u16* g, u16* l) {
  __builtin_amdgcn_global_load_lds(
      (const __attribute__((address_space(1))) void*)g,
      (__attribute__((address_space(3))) void*)l, 16, 0, 0);
}

// ---------------- elementwise: value fp32 -> bf16 ----------------
__global__ void cvt_value_kernel(const float* __restrict__ in, u16* __restrict__ out, int n4) {
  int idx = blockIdx.x * blockDim.x + threadIdx.x;
  int stride = gridDim.x * blockDim.x;
  for (int i = idx; i < n4; i += stride) {
    f32x4 v = reinterpret_cast<const f32x4*>(in)[i];
    u16x4 o = { f2bf(v[0]), f2bf(v[1]), f2bf(v[2]), f2bf(v[3]) };
    reinterpret_cast<u16x4*>(out)[i] = o;
  }
}

// ---------------- mask + cast weights ----------------
template<int MODE>
__global__ void mask_cvt_kernel(const float* __restrict__ in, u16* __restrict__ out, int n4) {
  const int shift = (MODE == 0) ? 11 : 12;
  const int cmask = (MODE == 0) ? 2047 : 4095;
  int idx0 = blockIdx.x * blockDim.x + threadIdx.x;
  int stride = gridDim.x * blockDim.x;
  for (int i = idx0; i < n4; i += stride) {
    int e0 = i * 4;
    int row = e0 >> shift;
    int col = e0 & cmask;
    int rdeg = row % 2047;
    f32x4 v = reinterpret_cast<const f32x4*>(in)[i];
    u16x4 o;
#pragma unroll
    for (int e = 0; e < 4; ++e) {
      int c = col + e;
      bool keep;
      if (MODE == 0)      keep = (c <= rdeg);
      else if (MODE == 1) keep = ((c % 2047) <= rdeg);
      else                keep = (row > (c % 2047));
      o[e] = keep ? f2bf(v[e]) : (u16)0;
    }
    reinterpret_cast<u16x4*>(out)[i] = o;
  }
}

// ============ 256x256 8-phase pipelined GEMM (G1/G2, EPI=relu+store) ========
// 512 thr = 8 waves (2M x 4N), per-wave 128x64 out. BK=64, dbuf LDS 128KB.
// Per K-tile: 4 phases (q-quadrant x ks-half), each: {ds_read 4-8 b128 ||
// stage unit || s_barrier || lgkmcnt(0) || setprio(1) 16 MFMA setprio(0) ||
// [gate vmcnt(counted)] || s_barrier}. Stage units per tile: u0=A[0,64),
// u1=A[128,192), u2=B[0,128), u3=B[128,256), u4=A[64,128), u5=A[192,256);
// streamed 4-6 phases ahead; gates vmcnt(5/6) @p1-end (u4,u5), vmcnt(4)
// @p3-end (next tile's u0..u3) -- never 0 in steady state. Two barriers per
// phase make all LDS WAR hazards barrier-proven. Zero-conflict swizzle:
// global source gsub = sub ^ (row&7), LDS dest linear (rule #21).
// Masked-skip: needed K-tiles = two dense runs, k0(j)=j*64+(j>=n1)*roff.
template<int MASKM>
__global__ __launch_bounds__(512, 2) void gemm256_kernel(
    const u16* __restrict__ A, const u16* __restrict__ Bw,
    const float* __restrict__ bias, u16* __restrict__ C,
    int M, int N, int K)
{
  __shared__ u16 ls[2][32768];   // per slot: A chunks [0,2048), B chunks [2048,4096)

  const int tid  = threadIdx.x;
  const int wid  = tid >> 6;
  const int lane = tid & 63;
  const int wm = wid >> 2, wn = wid & 3;
  const int l15 = lane & 15, lhi = lane >> 4;
  const int brow = blockIdx.y * 256;
  const int p = blockIdx.x;
  int cols[2];
  cols[0] = (p < 4) ? p : p + 4;
  cols[1] = (p < 4) ? 7 - p : 19 - p;

  const int arow_ = tid >> 3;                 // 0..63
  const int agsub = (tid & 7) ^ (arow_ & 7);  // pre-swizzled source sub-chunk
  // A-unit global bases (idx 0:u0 R=0, 1:u1 R=128, 2:u4 R=64, 3:u5 R=192)
  size_t aB[4];
  aB[0] = (size_t)(brow +   0 + arow_) * K + agsub * 8;
  aB[1] = (size_t)(brow + 128 + arow_) * K + agsub * 8;
  aB[2] = (size_t)(brow +  64 + arow_) * K + agsub * 8;
  aB[3] = (size_t)(brow + 192 + arow_) * K + agsub * 8;
  const int aCh[4] = {0, 1024, 512, 1536};    // LDS chunk bases

#pragma unroll 1
  for (int t = 0; t < 2; ++t) {
    const int bcol = cols[t] * 256;

    int rmax;
    {
      int sC = bcol, e = bcol + 255;
      if (e <= 2046)       rmax = e;
      else if (sC <= 2046) rmax = 2046;
      else { int em = e - 2047; rmax = (em <= 2046) ? em : 2046; }
    }
    int r1end = ((rmax >> 6) + 1) << 6; if (r1end > K) r1end = K;
    int run2start, r2end;
    if (MASKM == 1) { run2start = r1end; r2end = r1end; }
    else {
      run2start = (1984 > r1end) ? 1984 : r1end;
      r2end = (((2047 + rmax) >> 6) + 1) << 6; if (r2end > K) r2end = K;
      if (r2end < run2start) r2end = run2start;
    }
    const int n1 = r1end >> 6;
    const int nt = n1 + ((r2end - run2start) >> 6);
    const int roff = run2start - r1end;

    // B-unit global bases (u in {0,1} -> rows u*128.., c chunk half)
    size_t bB[2][2];
#pragma unroll
    for (int u = 0; u < 2; ++u)
#pragma unroll
      for (int c = 0; c < 2; ++c)
        bB[u][c] = (size_t)(bcol + u * 128 + arow_ + 64 * c) * K + agsub * 8;

    floatx4 acc[8][4];
#pragma unroll
    for (int i = 0; i < 8; ++i)
#pragma unroll
      for (int j = 0; j < 4; ++j)
        acc[i][j] = (floatx4){0.f, 0.f, 0.f, 0.f};

#define K0F(j) (((j) << 6) + (((j) >= n1) ? roff : 0))
#define ST_A(slot_, idx_, k0v) glds16(A + aB[idx_] + (k0v), (u16*)&ls[slot_][(aCh[idx_] + tid) * 8])
#define ST_B(slot_, u_, k0v) do { \
      glds16(Bw + bB[u_][0] + (k0v), (u16*)&ls[slot_][(2048 + (u_) * 1024 + tid) * 8]); \
      glds16(Bw + bB[u_][1] + (k0v), (u16*)&ls[slot_][(2048 + (u_) * 1024 + tid + 512) * 8]); \
    } while (0)

    // ---- prologue: tile0 (u0,u1,u2,u3,u4,u5) + tile1 (u0,u1); gate vmcnt ----
    ST_A(0, 0, 0); ST_A(0, 1, 0);
    ST_B(0, 0, 0); ST_B(0, 1, 0);
    ST_A(0, 2, 0); ST_A(0, 3, 0);
    if (nt > 1) {
      const int k1p = K0F(1);
      ST_A(1, 0, k1p); ST_A(1, 1, k1p);
      asm volatile("s_waitcnt vmcnt(4)" ::: "memory");
    } else {
      asm volatile("s_waitcnt vmcnt(2)" ::: "memory");
    }
    __builtin_amdgcn_sched_barrier(0);
    __builtin_amdgcn_s_barrier();

#pragma unroll 1
    for (int i = 0; i < nt; ++i) {
      const int s = i & 1, o = s ^ 1;
      const u16* sA = &ls[s][0];
      const u16* sB = &ls[s][16384];
      const bool g1 = (i + 1 < nt), g2 = (i + 2 < nt);
      const int k1 = g1 ? K0F(i + 1) : 0;
      const int k2 = g2 ? K0F(i + 2) : 0;
      short8 af[4], bf0[4], bf1[4];

#define RD_A(q_, ks_) do { \
        _Pragma("unroll") \
        for (int mi = 0; mi < 4; ++mi) { \
          int row = wm * 128 + (q_) * 64 + mi * 16 + l15; \
          int ch = row * 8 + (((ks_) * 4 + lhi) ^ (row & 7)); \
          af[mi] = *(const short8*)&sA[ch * 8]; \
        } } while (0)
#define RD_B(ks_, dst_) do { \
        _Pragma("unroll") \
        for (int ni = 0; ni < 4; ++ni) { \
          int row = wn * 64 + ni * 16 + l15; \
          int ch = row * 8 + (((ks_) * 4 + lhi) ^ (row & 7)); \
          dst_[ni] = *(const short8*)&sB[ch * 8]; \
        } } while (0)
#define MFMA16(q_, bf_) do { \
        _Pragma("unroll") \
        for (int mi = 0; mi < 4; ++mi) \
          _Pragma("unroll") \
          for (int ni = 0; ni < 4; ++ni) \
            acc[(q_) * 4 + mi][ni] = __builtin_amdgcn_mfma_f32_16x16x32_bf16( \
                af[mi], bf_[ni], acc[(q_) * 4 + mi][ni], 0, 0, 0); \
        } while (0)

      // ---------- phase 0: q0 ks0 ----------
      RD_A(0, 0);
      RD_B(0, bf0);
      if (g1) ST_B(o, 0, k1);
      __builtin_amdgcn_s_barrier();
      asm volatile("s_waitcnt lgkmcnt(0)" ::: "memory");
      __builtin_amdgcn_sched_barrier(0);
      __builtin_amdgcn_s_setprio(1);
      MFMA16(0, bf0);
      __builtin_amdgcn_s_setprio(0);
      __builtin_amdgcn_s_barrier();

      // ---------- phase 1: q0 ks1 ----------
      RD_A(0, 1);
      RD_B(1, bf1);
      if (g1) ST_B(o, 1, k1);
      __builtin_amdgcn_s_barrier();
      asm volatile("s_waitcnt lgkmcnt(0)" ::: "memory");
      __builtin_amdgcn_sched_barrier(0);
      __builtin_amdgcn_s_setprio(1);
      MFMA16(0, bf1);
      __builtin_amdgcn_s_setprio(0);
      // gate: u4,u5(i) must be landed before phase-2 reads
      if (g1) {
        if (i == 0) asm volatile("s_waitcnt vmcnt(6)" ::: "memory");
        else        asm volatile("s_waitcnt vmcnt(5)" ::: "memory");
      } else {
        asm volatile("s_waitcnt vmcnt(0)" ::: "memory");
      }
      __builtin_amdgcn_sched_barrier(0);
      __builtin_amdgcn_s_barrier();

      // ---------- phase 2: q1 ks0 ----------
      RD_A(1, 0);
      if (g1) ST_A(o, 2, k1);
      if (g2) ST_A(s, 0, k2);
      __builtin_amdgcn_s_barrier();
      asm volatile("s_waitcnt lgkmcnt(0)" ::: "memory");
      __builtin_amdgcn_sched_barrier(0);
      __builtin_amdgcn_s_setprio(1);
      MFMA16(1, bf0);
      __builtin_amdgcn_s_setprio(0);
      __builtin_amdgcn_s_barrier();

      // ---------- phase 3: q1 ks1 ----------
      RD_A(1, 1);
      if (g1) ST_A(o, 3, k1);
      if (g2) ST_A(s, 1, k2);
      __builtin_amdgcn_s_barrier();
      asm volatile("s_waitcnt lgkmcnt(0)" ::: "memory");
      __builtin_amdgcn_sched_barrier(0);
      __builtin_amdgcn_s_setprio(1);
      MFMA16(1, bf1);
      __builtin_amdgcn_s_setprio(0);
      // gate: u0..u3(i+1) must be landed before next phase-0 reads
      if (g1) {
        if (g2) asm volatile("s_waitcnt vmcnt(4)" ::: "memory");
        else    asm volatile("s_waitcnt vmcnt(2)" ::: "memory");
        __builtin_amdgcn_sched_barrier(0);
      }
      __builtin_amdgcn_s_barrier();
#undef RD_A
#undef RD_B
#undef MFMA16
    }

    // ---------- epilogue: C = relu(acc + bias) ----------
#pragma unroll
    for (int mi = 0; mi < 8; ++mi) {
      int row = brow + wm * 128 + (mi >> 2) * 64 + (mi & 3) * 16 + lhi * 4;
#pragma unroll
      for (int ni = 0; ni < 4; ++ni) {
        int col = bcol + wn * 64 + ni * 16 + l15;
        float bv = bias[col];
#pragma unroll
        for (int e = 0; e < 4; ++e) {
          float v = acc[mi][ni][e] + bv;
          v = fmaxf(v, 0.0f);
          C[(size_t)(row + e) * N + col] = f2bf(v);
        }
      }
    }
    __syncthreads();
#undef K0F
#undef ST_A
#undef ST_B
  }
}

// ---------------- round-6 GEMM (used for G3 only) ----------------
template<int EPI, int MASK, int BM>
__global__ __launch_bounds__(256) void gemm_kernel(
    const u16* __restrict__ A,
    const u16* __restrict__ Bw,
    const float* __restrict__ bias,
    u16* __restrict__ C,
    const float* __restrict__ value,
    float* __restrict__ outp,
    int M, int N, int K)
{
  constexpr int MI  = BM / 32;
  constexpr int APT = BM / 32;
  __shared__ u16 lsA[BM * 64];
  __shared__ u16 lsB[128 * 64];

  const int tid  = threadIdx.x;
  const int wave = tid >> 6;
  const int lane = tid & 63;
  const int wr = wave >> 1;
  const int wc = wave & 1;
  const int l15 = lane & 15;
  const int lhi = lane >> 4;
  const int brow = blockIdx.y * BM;

  const int p = blockIdx.x;
  int cols[2];
  if (gridDim.x == 16) {
    cols[0] = (p < 8) ? p : p + 8;
    cols[1] = (p < 8) ? 15 - p : 39 - p;
  } else {
    cols[0] = p;
    cols[1] = 15 - p;
  }

  size_t aOff[APT]; u16* aDst[APT];
#pragma unroll
  for (int u = 0; u < APT; ++u) {
    int ch = tid + 256 * u;
    int row = ch >> 3, sub = ch & 7;
    int ssub = sub ^ (row & 7);
    aOff[u] = (size_t)(brow + row) * K + ssub * 8;
    aDst[u] = &lsA[ch * 8];
  }
  int bRow[4], bSsub[4]; u16* bDst[4];
#pragma unroll
  for (int u = 0; u < 4; ++u) {
    int ch = tid + 256 * u;
    int row = ch >> 3, sub = ch & 7;
    bRow[u] = row;
    bSsub[u] = sub ^ (row & 7);
    bDst[u] = &lsB[ch * 8];
  }

#pragma unroll
  for (int t = 0; t < 2; ++t) {
    const int bcol = cols[t] * 128;

    int rmax;
    {
      int s = bcol, e = bcol + 127;
      if (MASK == 3) {
        rmax = bcol + 126;
      } else {
        if (e <= 2046)      rmax = e;
        else if (s <= 2046) rmax = 2046;
        else {
          int em = e - 2047;
          rmax = (em <= 2046) ? em : 2046;
        }
      }
    }

    size_t bOff[4];
#pragma unroll
    for (int u = 0; u < 4; ++u)
      bOff[u] = (size_t)(bcol + bRow[u]) * K + bSsub[u] * 8;

    floatx4 acc[MI][4];
#pragma unroll
    for (int i = 0; i < MI; ++i)
#pragma unroll
      for (int j = 0; j < 4; ++j)
        acc[i][j] = (floatx4){0.f, 0.f, 0.f, 0.f};

    for (int k0 = 0; k0 < K; k0 += 64) {
      bool needed;
      if (MASK == 1) {
        needed = (k0 <= rmax);
        if (!needed) break;
      } else {
        int m = (k0 >= 2047) ? (k0 - 2047) : k0;
        int mn = (m + 63 >= 2047) ? 0 : m;
        needed = (mn <= rmax);
      }
      if (!needed) continue;

#pragma unroll
      for (int u = 0; u < APT; ++u) glds16(A + aOff[u] + k0, aDst[u]);
#pragma unroll
      for (int u = 0; u < 4; ++u)   glds16(Bw + bOff[u] + k0, bDst[u]);
      __syncthreads();

#pragma unroll
      for (int ks = 0; ks < 2; ++ks) {
        short8 af[MI], bfv[4];
#pragma unroll
        for (int mi = 0; mi < MI; ++mi) {
          int row = wr * (BM / 2) + mi * 16 + l15;
          af[mi] = *(const short8*)&lsA[row * 64 + (((ks * 4 + lhi) ^ (row & 7)) * 8)];
        }
#pragma unroll
        for (int ni = 0; ni < 4; ++ni) {
          int row = wc * 64 + ni * 16 + l15;
          bfv[ni] = *(const short8*)&lsB[row * 64 + (((ks * 4 + lhi) ^ (row & 7)) * 8)];
        }
#pragma unroll
        for (int mi = 0; mi < MI; ++mi)
#pragma unroll
          for (int ni = 0; ni < 4; ++ni)
            acc[mi][ni] = __builtin_amdgcn_mfma_f32_16x16x32_bf16(af[mi], bfv[ni], acc[mi][ni], 0, 0, 0);
      }
      __syncthreads();
    }

    if (EPI == 0) {
#pragma unroll
      for (int mi = 0; mi < MI; ++mi) {
        int row = brow + wr * (BM / 2) + mi * 16 + lhi * 4;
#pragma unroll
        for (int ni = 0; ni < 4; ++ni) {
          int col = bcol + wc * 64 + ni * 16 + l15;
          float bv = bias[col];
#pragma unroll
          for (int e = 0; e < 4; ++e) {
            float v = acc[mi][ni][e] + bv;
            v = fmaxf(v, 0.0f);
            C[(size_t)(row + e) * N + col] = f2bf(v);
          }
        }
      }
    } else {
#pragma unroll
      for (int mi = 0; mi < MI; ++mi) {
#pragma unroll
        for (int e = 0; e < 4; ++e) {
          int row = brow + wr * (BM / 2) + mi * 16 + lhi * 4 + e;
          float partial = 0.0f;
#pragma unroll
          for (int ni = 0; ni < 4; ++ni) {
            int col = bcol + wc * 64 + ni * 16 + l15;
            float l = acc[mi][ni][e] + bias[col];
            float v = value[(size_t)row * N + col];
            float sp = fmaxf(l, 0.0f) + __logf(1.0f + __expf(-fabsf(l)));
            partial += v * l - sp;
          }
#pragma unroll
          for (int off = 1; off < 16; off <<= 1)
            partial += __shfl_xor(partial, off, 64);
          if (l15 == 0) atomicAdd(&outp[row], partial);
        }
      }
    }
  }
}

// ---------------- launcher ----------------
extern "C" void kernel_launch(void* const* d_in, const int* in_sizes, int n_in,
                              void* d_out, int out_size, void* d_ws, size_t ws_size,
                              hipStream_t stream) {
  const float* value = (const float*)d_in[0];
  const float* W1 = (const float*)d_in[1];
  const float* b1 = (const float*)d_in[2];
  const float* W2 = (const float*)d_in[3];
  const float* b2 = (const float*)d_in[4];
  const float* W3 = (const float*)d_in[5];
  const float* b3 = (const float*)d_in[6];
  float* out = (float*)d_out;

  char* ws = (char*)d_ws;
  u16* vbf = (u16*)(ws);                        // B*D bf16
  u16* w1m = (u16*)(ws + 33554432ULL);          // H*D bf16
  u16* w2m = (u16*)(ws + 50331648ULL);          // H*H bf16
  u16* w3m = (u16*)(ws + 83886080ULL);          // D*H bf16
  u16* h1  = (u16*)(ws + 100663296ULL);         // B*H bf16
  u16* h2  = (u16*)(ws + 167772160ULL);         // B*H bf16

  hipMemsetAsync(d_out, 0, (size_t)out_size * sizeof(float), stream);

  cvt_value_kernel<<<2048, 256, 0, stream>>>(value, vbf, (BB * DD) / 4);
  mask_cvt_kernel<0><<<2048, 256, 0, stream>>>(W1, w1m, (HH * DD) / 4);
  mask_cvt_kernel<1><<<2048, 256, 0, stream>>>(W2, w2m, (HH * HH) / 4);
  mask_cvt_kernel<2><<<2048, 256, 0, stream>>>(W3, w3m, (DD * HH) / 4);

  dim3 g12(8, BB / 256);
  gemm256_kernel<1><<<g12, 512, 0, stream>>>(vbf, w1m, b1, h1, BB, HH, DD);
  gemm256_kernel<2><<<g12, 512, 0, stream>>>(h1, w2m, b2, h2, BB, HH, HH);
  dim3 g3(8, BB / 64);
  gemm_kernel<1, 3, 64><<<g3, 256, 0, stream>>>(h2, w3m, b3, nullptr, value, out, BB, DD, HH);
}

// Round 9
// 402.618 us; speedup vs baseline: 1.2963x; 1.1153x over previous
//
#include <hip/hip_runtime.h>
#include <hip/hip_bf16.h>
#include <cstdint>

typedef short short8 __attribute__((ext_vector_type(8)));
typedef float floatx4 __attribute__((ext_vector_type(4)));
typedef float f32x4 __attribute__((ext_vector_type(4)));
typedef unsigned short u16;
typedef unsigned short u16x4 __attribute__((ext_vector_type(4)));

#define BB 8192
#define DD 2048
#define HH 4096

static __device__ __forceinline__ u16 f2bf(float x) {
  __hip_bfloat16 h = __float2bfloat16(x);
  return __builtin_bit_cast(u16, h);
}

static __device__ __forceinline__ float bf2f(u16 x) {
  unsigned int u = ((unsigned int)x) << 16;
  return __builtin_bit_cast(float, u);
}

static __device__ __forceinline__ void glds16(const u16* g, u16* l) {
  __builtin_amdgcn_global_load_lds(
      (const __attribute__((address_space(1))) void*)g,
      (__attribute__((address_space(3))) void*)l, 16, 0, 0);
}

// ---------------- elementwise: value fp32 -> bf16 ----------------
__global__ void cvt_value_kernel(const float* __restrict__ in, u16* __restrict__ out, int n4) {
  int idx = blockIdx.x * blockDim.x + threadIdx.x;
  int stride = gridDim.x * blockDim.x;
  for (int i = idx; i < n4; i += stride) {
    f32x4 v = reinterpret_cast<const f32x4*>(in)[i];
    u16x4 o = { f2bf(v[0]), f2bf(v[1]), f2bf(v[2]), f2bf(v[3]) };
    reinterpret_cast<u16x4*>(out)[i] = o;
  }
}

// ---------------- mask + cast weights ----------------
template<int MODE>
__global__ void mask_cvt_kernel(const float* __restrict__ in, u16* __restrict__ out, int n4) {
  const int shift = (MODE == 0) ? 11 : 12;
  const int cmask = (MODE == 0) ? 2047 : 4095;
  int idx0 = blockIdx.x * blockDim.x + threadIdx.x;
  int stride = gridDim.x * blockDim.x;
  for (int i = idx0; i < n4; i += stride) {
    int e0 = i * 4;
    int row = e0 >> shift;
    int col = e0 & cmask;
    int rdeg = row % 2047;
    f32x4 v = reinterpret_cast<const f32x4*>(in)[i];
    u16x4 o;
#pragma unroll
    for (int e = 0; e < 4; ++e) {
      int c = col + e;
      bool keep;
      if (MODE == 0)      keep = (c <= rdeg);
      else if (MODE == 1) keep = ((c % 2047) <= rdeg);
      else                keep = (row > (c % 2047));
      o[e] = keep ? f2bf(v[e]) : (u16)0;
    }
    reinterpret_cast<u16x4*>(out)[i] = o;
  }
}

// ============ 256x256 8-phase pipelined GEMM (G1/G2, EPI=relu+store) ========
template<int MASKM>
__global__ __launch_bounds__(512, 2) void gemm256_kernel(
    const u16* __restrict__ A, const u16* __restrict__ Bw,
    const float* __restrict__ bias, u16* __restrict__ C,
    int M, int N, int K)
{
  __shared__ u16 ls[2][32768];   // per slot: A chunks [0,2048), B chunks [2048,4096)

  const int tid  = threadIdx.x;
  const int wid  = tid >> 6;
  const int lane = tid & 63;
  const int wm = wid >> 2, wn = wid & 3;
  const int l15 = lane & 15, lhi = lane >> 4;
  const int brow = blockIdx.y * 256;
  const int p = blockIdx.x;
  int cols[2];
  cols[0] = (p < 4) ? p : p + 4;
  cols[1] = (p < 4) ? 7 - p : 19 - p;

  const int arow_ = tid >> 3;                 // 0..63
  const int agsub = (tid & 7) ^ (arow_ & 7);  // pre-swizzled source sub-chunk
  size_t aB[4];
  aB[0] = (size_t)(brow +   0 + arow_) * K + agsub * 8;
  aB[1] = (size_t)(brow + 128 + arow_) * K + agsub * 8;
  aB[2] = (size_t)(brow +  64 + arow_) * K + agsub * 8;
  aB[3] = (size_t)(brow + 192 + arow_) * K + agsub * 8;
  const int aCh[4] = {0, 1024, 512, 1536};    // LDS chunk bases

#pragma unroll 1
  for (int t = 0; t < 2; ++t) {
    const int bcol = cols[t] * 256;

    int rmax;
    {
      int sC = bcol, e = bcol + 255;
      if (e <= 2046)       rmax = e;
      else if (sC <= 2046) rmax = 2046;
      else { int em = e - 2047; rmax = (em <= 2046) ? em : 2046; }
    }
    int r1end = ((rmax >> 6) + 1) << 6; if (r1end > K) r1end = K;
    int run2start, r2end;
    if (MASKM == 1) { run2start = r1end; r2end = r1end; }
    else {
      run2start = (1984 > r1end) ? 1984 : r1end;
      r2end = (((2047 + rmax) >> 6) + 1) << 6; if (r2end > K) r2end = K;
      if (r2end < run2start) r2end = run2start;
    }
    const int n1 = r1end >> 6;
    const int nt = n1 + ((r2end - run2start) >> 6);
    const int roff = run2start - r1end;

    size_t bB[2][2];
#pragma unroll
    for (int u = 0; u < 2; ++u)
#pragma unroll
      for (int c = 0; c < 2; ++c)
        bB[u][c] = (size_t)(bcol + u * 128 + arow_ + 64 * c) * K + agsub * 8;

    floatx4 acc[8][4];
#pragma unroll
    for (int i = 0; i < 8; ++i)
#pragma unroll
      for (int j = 0; j < 4; ++j)
        acc[i][j] = (floatx4){0.f, 0.f, 0.f, 0.f};

#define K0F(j) (((j) << 6) + (((j) >= n1) ? roff : 0))
#define ST_A(slot_, idx_, k0v) glds16(A + aB[idx_] + (k0v), (u16*)&ls[slot_][(aCh[idx_] + tid) * 8])
#define ST_B(slot_, u_, k0v) do { \
      glds16(Bw + bB[u_][0] + (k0v), (u16*)&ls[slot_][(2048 + (u_) * 1024 + tid) * 8]); \
      glds16(Bw + bB[u_][1] + (k0v), (u16*)&ls[slot_][(2048 + (u_) * 1024 + tid + 512) * 8]); \
    } while (0)

    ST_A(0, 0, 0); ST_A(0, 1, 0);
    ST_B(0, 0, 0); ST_B(0, 1, 0);
    ST_A(0, 2, 0); ST_A(0, 3, 0);
    if (nt > 1) {
      const int k1p = K0F(1);
      ST_A(1, 0, k1p); ST_A(1, 1, k1p);
      asm volatile("s_waitcnt vmcnt(4)" ::: "memory");
    } else {
      asm volatile("s_waitcnt vmcnt(2)" ::: "memory");
    }
    __builtin_amdgcn_sched_barrier(0);
    __builtin_amdgcn_s_barrier();

#pragma unroll 1
    for (int i = 0; i < nt; ++i) {
      const int s = i & 1, o = s ^ 1;
      const u16* sA = &ls[s][0];
      const u16* sB = &ls[s][16384];
      const bool g1 = (i + 1 < nt), g2 = (i + 2 < nt);
      const int k1 = g1 ? K0F(i + 1) : 0;
      const int k2 = g2 ? K0F(i + 2) : 0;
      short8 af[4], bf0[4], bf1[4];

#define RD_A(q_, ks_) do { \
        _Pragma("unroll") \
        for (int mi = 0; mi < 4; ++mi) { \
          int row = wm * 128 + (q_) * 64 + mi * 16 + l15; \
          int ch = row * 8 + (((ks_) * 4 + lhi) ^ (row & 7)); \
          af[mi] = *(const short8*)&sA[ch * 8]; \
        } } while (0)
#define RD_B(ks_, dst_) do { \
        _Pragma("unroll") \
        for (int ni = 0; ni < 4; ++ni) { \
          int row = wn * 64 + ni * 16 + l15; \
          int ch = row * 8 + (((ks_) * 4 + lhi) ^ (row & 7)); \
          dst_[ni] = *(const short8*)&sB[ch * 8]; \
        } } while (0)
#define MFMA16(q_, bf_) do { \
        _Pragma("unroll") \
        for (int mi = 0; mi < 4; ++mi) \
          _Pragma("unroll") \
          for (int ni = 0; ni < 4; ++ni) \
            acc[(q_) * 4 + mi][ni] = __builtin_amdgcn_mfma_f32_16x16x32_bf16( \
                af[mi], bf_[ni], acc[(q_) * 4 + mi][ni], 0, 0, 0); \
        } while (0)

      // ---------- phase 0: q0 ks0 ----------
      RD_A(0, 0);
      RD_B(0, bf0);
      if (g1) ST_B(o, 0, k1);
      __builtin_amdgcn_s_barrier();
      asm volatile("s_waitcnt lgkmcnt(0)" ::: "memory");
      __builtin_amdgcn_sched_barrier(0);
      __builtin_amdgcn_s_setprio(1);
      MFMA16(0, bf0);
      __builtin_amdgcn_s_setprio(0);
      __builtin_amdgcn_s_barrier();

      // ---------- phase 1: q0 ks1 ----------
      RD_A(0, 1);
      RD_B(1, bf1);
      if (g1) ST_B(o, 1, k1);
      __builtin_amdgcn_s_barrier();
      asm volatile("s_waitcnt lgkmcnt(0)" ::: "memory");
      __builtin_amdgcn_sched_barrier(0);
      __builtin_amdgcn_s_setprio(1);
      MFMA16(0, bf1);
      __builtin_amdgcn_s_setprio(0);
      if (g1) {
        if (i == 0) asm volatile("s_waitcnt vmcnt(6)" ::: "memory");
        else        asm volatile("s_waitcnt vmcnt(5)" ::: "memory");
      } else {
        asm volatile("s_waitcnt vmcnt(0)" ::: "memory");
      }
      __builtin_amdgcn_sched_barrier(0);
      __builtin_amdgcn_s_barrier();

      // ---------- phase 2: q1 ks0 ----------
      RD_A(1, 0);
      if (g1) ST_A(o, 2, k1);
      if (g2) ST_A(s, 0, k2);
      __builtin_amdgcn_s_barrier();
      asm volatile("s_waitcnt lgkmcnt(0)" ::: "memory");
      __builtin_amdgcn_sched_barrier(0);
      __builtin_amdgcn_s_setprio(1);
      MFMA16(1, bf0);
      __builtin_amdgcn_s_setprio(0);
      __builtin_amdgcn_s_barrier();

      // ---------- phase 3: q1 ks1 ----------
      RD_A(1, 1);
      if (g1) ST_A(o, 3, k1);
      if (g2) ST_A(s, 1, k2);
      __builtin_amdgcn_s_barrier();
      asm volatile("s_waitcnt lgkmcnt(0)" ::: "memory");
      __builtin_amdgcn_sched_barrier(0);
      __builtin_amdgcn_s_setprio(1);
      MFMA16(1, bf1);
      __builtin_amdgcn_s_setprio(0);
      if (g1) {
        if (g2) asm volatile("s_waitcnt vmcnt(4)" ::: "memory");
        else    asm volatile("s_waitcnt vmcnt(2)" ::: "memory");
        __builtin_amdgcn_sched_barrier(0);
      }
      __builtin_amdgcn_s_barrier();
#undef RD_A
#undef RD_B
#undef MFMA16
    }

    // ---------- epilogue: C = relu(acc + bias) ----------
#pragma unroll
    for (int mi = 0; mi < 8; ++mi) {
      int row = brow + wm * 128 + (mi >> 2) * 64 + (mi & 3) * 16 + lhi * 4;
#pragma unroll
      for (int ni = 0; ni < 4; ++ni) {
        int col = bcol + wn * 64 + ni * 16 + l15;
        float bv = bias[col];
#pragma unroll
        for (int e = 0; e < 4; ++e) {
          float v = acc[mi][ni][e] + bv;
          v = fmaxf(v, 0.0f);
          C[(size_t)(row + e) * N + col] = f2bf(v);
        }
      }
    }
    __syncthreads();
#undef K0F
#undef ST_A
#undef ST_B
  }
}

// ============ G3: 64x256 wide-N GEMM + logprob epilogue ====================
// BM=64 rows, BN=256 cols (two adjacent 128-col tiles; their needed-k ranges
// are nested, union = heavier tile, extra k multiply stored zeros -> exact).
// 4 waves (2Mx2N): wave tile 32x128, acc 2x8 frags, 32 MFMA per barrier pair
// (= the proven round-6 G2 geometry). Super-pair {sg=q, sg=7-q} balances
// (nt = 73/74/74/74). Grid 4 x 128 = 512 blocks = 2/CU (LDS 40KB).
// Zero-conflict swizzle: source sub ^= row&7, LDS linear, read same XOR.
// Epilogue: l = acc+bias; partial = v*l - softplus(l), v from vbf (bf16,
// exact 0/1); 16-lane shuffle reduce; atomicAdd per (row, 128-col half).
__global__ __launch_bounds__(256) void gemm3_kernel(
    const u16* __restrict__ A,      // h2: BB x HH
    const u16* __restrict__ Bw,     // w3m: DD x HH
    const float* __restrict__ bias, // b3
    const u16* __restrict__ vbf,    // value bf16: BB x DD
    float* __restrict__ outp,       // BB
    int M, int N, int K)
{
  __shared__ u16 lsA[64 * 64];      // 8 KB
  __shared__ u16 lsB[256 * 64];     // 32 KB

  const int tid  = threadIdx.x;
  const int wave = tid >> 6;
  const int lane = tid & 63;
  const int wr = wave >> 1;         // M half (32 rows)
  const int wc = wave & 1;          // N half (128 cols)
  const int l15 = lane & 15;
  const int lhi = lane >> 4;
  const int brow = blockIdx.y * 64;

  const int q = blockIdx.x;         // 0..3
  int sgs[2] = { q, 7 - q };

  // A staging: 512 chunks (64 rows x 8 sub), 2 per thread
  size_t aOff[2]; u16* aDst[2];
#pragma unroll
  for (int u = 0; u < 2; ++u) {
    int ch = tid + 256 * u;
    int row = ch >> 3, sub = ch & 7;
    int ssub = sub ^ (row & 7);
    aOff[u] = (size_t)(brow + row) * K + ssub * 8;
    aDst[u] = &lsA[ch * 8];
  }
  // B staging: 2048 chunks (256 rows x 8 sub), 8 per thread
  int bRow[8], bSsub[8]; u16* bDst[8];
#pragma unroll
  for (int u = 0; u < 8; ++u) {
    int ch = tid + 256 * u;
    int row = ch >> 3, sub = ch & 7;
    bRow[u] = row;
    bSsub[u] = sub ^ (row & 7);
    bDst[u] = &lsB[ch * 8];
  }

#pragma unroll 1
  for (int t = 0; t < 2; ++t) {
    const int sg = sgs[t];
    const int bcol = sg * 256;
    const int rmax = bcol + 254;    // keep k%2047 <= row-1; max row = bcol+255

    int r1end = ((rmax >> 6) + 1) << 6; if (r1end > K) r1end = K;
    int run2start = (1984 > r1end) ? 1984 : r1end;
    int r2end = (((2047 + rmax) >> 6) + 1) << 6; if (r2end > K) r2end = K;
    if (r2end < run2start) r2end = run2start;
    const int n1 = r1end >> 6;
    const int nt = n1 + ((r2end - run2start) >> 6);
    const int roff = run2start - r1end;

    size_t bOff[8];
#pragma unroll
    for (int u = 0; u < 8; ++u)
      bOff[u] = (size_t)(bcol + bRow[u]) * K + bSsub[u] * 8;

    floatx4 acc[2][8];
#pragma unroll
    for (int i = 0; i < 2; ++i)
#pragma unroll
      for (int j = 0; j < 8; ++j)
        acc[i][j] = (floatx4){0.f, 0.f, 0.f, 0.f};

#pragma unroll 1
    for (int i = 0; i < nt; ++i) {
      const int k0 = (i << 6) + ((i >= n1) ? roff : 0);
#pragma unroll
      for (int u = 0; u < 2; ++u) glds16(A + aOff[u] + k0, aDst[u]);
#pragma unroll
      for (int u = 0; u < 8; ++u) glds16(Bw + bOff[u] + k0, bDst[u]);
      __syncthreads();

#pragma unroll
      for (int ks = 0; ks < 2; ++ks) {
        short8 af[2], bfv[8];
#pragma unroll
        for (int mi = 0; mi < 2; ++mi) {
          int row = wr * 32 + mi * 16 + l15;
          af[mi] = *(const short8*)&lsA[row * 64 + (((ks * 4 + lhi) ^ (row & 7)) * 8)];
        }
#pragma unroll
        for (int ni = 0; ni < 8; ++ni) {
          int row = wc * 128 + ni * 16 + l15;
          bfv[ni] = *(const short8*)&lsB[row * 64 + (((ks * 4 + lhi) ^ (row & 7)) * 8)];
        }
#pragma unroll
        for (int mi = 0; mi < 2; ++mi)
#pragma unroll
          for (int ni = 0; ni < 8; ++ni)
            acc[mi][ni] = __builtin_amdgcn_mfma_f32_16x16x32_bf16(af[mi], bfv[ni], acc[mi][ni], 0, 0, 0);
      }
      __syncthreads();
    }

    // ---------- logprob epilogue ----------
#pragma unroll
    for (int mi = 0; mi < 2; ++mi) {
#pragma unroll
      for (int e = 0; e < 4; ++e) {
        int row = brow + wr * 32 + mi * 16 + lhi * 4 + e;
        float partial = 0.0f;
#pragma unroll
        for (int ni = 0; ni < 8; ++ni) {
          int col = bcol + wc * 128 + ni * 16 + l15;
          float l = acc[mi][ni][e] + bias[col];
          float v = bf2f(vbf[(size_t)row * DD + col]);
          float sp = fmaxf(l, 0.0f) + __logf(1.0f + __expf(-fabsf(l)));
          partial += v * l - sp;
        }
#pragma unroll
        for (int off = 1; off < 16; off <<= 1)
          partial += __shfl_xor(partial, off, 64);
        if (l15 == 0) atomicAdd(&outp[row], partial);
      }
    }
  }
}

// ---------------- launcher ----------------
extern "C" void kernel_launch(void* const* d_in, const int* in_sizes, int n_in,
                              void* d_out, int out_size, void* d_ws, size_t ws_size,
                              hipStream_t stream) {
  const float* value = (const float*)d_in[0];
  const float* W1 = (const float*)d_in[1];
  const float* b1 = (const float*)d_in[2];
  const float* W2 = (const float*)d_in[3];
  const float* b2 = (const float*)d_in[4];
  const float* W3 = (const float*)d_in[5];
  const float* b3 = (const float*)d_in[6];
  float* out = (float*)d_out;

  char* ws = (char*)d_ws;
  u16* vbf = (u16*)(ws);                        // B*D bf16
  u16* w1m = (u16*)(ws + 33554432ULL);          // H*D bf16
  u16* w2m = (u16*)(ws + 50331648ULL);          // H*H bf16
  u16* w3m = (u16*)(ws + 83886080ULL);          // D*H bf16
  u16* h1  = (u16*)(ws + 100663296ULL);         // B*H bf16
  u16* h2  = (u16*)(ws + 167772160ULL);         // B*H bf16

  hipMemsetAsync(d_out, 0, (size_t)out_size * sizeof(float), stream);

  cvt_value_kernel<<<2048, 256, 0, stream>>>(value, vbf, (BB * DD) / 4);
  mask_cvt_kernel<0><<<2048, 256, 0, stream>>>(W1, w1m, (HH * DD) / 4);
  mask_cvt_kernel<1><<<2048, 256, 0, stream>>>(W2, w2m, (HH * HH) / 4);
  mask_cvt_kernel<2><<<2048, 256, 0, stream>>>(W3, w3m, (DD * HH) / 4);

  dim3 g12(8, BB / 256);
  gemm256_kernel<1><<<g12, 512, 0, stream>>>(vbf, w1m, b1, h1, BB, HH, DD);
  gemm256_kernel<2><<<g12, 512, 0, stream>>>(h1, w2m, b2, h2, BB, HH, HH);
  dim3 g3(4, BB / 64);
  gemm3_kernel<<<g3, 256, 0, stream>>>(h2, w3m, b3, vbf, out, BB, DD, HH);
}

// Round 10
// 395.633 us; speedup vs baseline: 1.3192x; 1.0177x over previous
//
#include <hip/hip_runtime.h>
#include <hip/hip_bf16.h>
#include <cstdint>

typedef short short8 __attribute__((ext_vector_type(8)));
typedef float floatx4 __attribute__((ext_vector_type(4)));
typedef float f32x4 __attribute__((ext_vector_type(4)));
typedef unsigned short u16;
typedef unsigned short u16x4 __attribute__((ext_vector_type(4)));

#define BB 8192
#define DD 2048
#define HH 4096

static __device__ __forceinline__ u16 f2bf(float x) {
  __hip_bfloat16 h = __float2bfloat16(x);
  return __builtin_bit_cast(u16, h);
}

static __device__ __forceinline__ float bf2f(u16 x) {
  unsigned int u = ((unsigned int)x) << 16;
  return __builtin_bit_cast(float, u);
}

static __device__ __forceinline__ void glds16(const u16* g, u16* l) {
  __builtin_amdgcn_global_load_lds(
      (const __attribute__((address_space(1))) void*)g,
      (__attribute__((address_space(3))) void*)l, 16, 0, 0);
}

// ---------------- elementwise: value fp32 -> bf16 ----------------
__global__ void cvt_value_kernel(const float* __restrict__ in, u16* __restrict__ out, int n4) {
  int idx = blockIdx.x * blockDim.x + threadIdx.x;
  int stride = gridDim.x * blockDim.x;
  for (int i = idx; i < n4; i += stride) {
    f32x4 v = reinterpret_cast<const f32x4*>(in)[i];
    u16x4 o = { f2bf(v[0]), f2bf(v[1]), f2bf(v[2]), f2bf(v[3]) };
    reinterpret_cast<u16x4*>(out)[i] = o;
  }
}

// ---------------- tiled mask + cast weights (64x64 tiles) ----------------
// MODE 0: W1 (HxD),  keep c <= r%2047
// MODE 1: W2 (HxH),  keep c%2047 <= r%2047
// MODE 2: W3 (DxH),  keep r > c%2047
// All-zero tiles (closed-form, wrap-exact: deg wraps at 2047 AND 4094) write
// zeros WITHOUT reading the fp32 source (~45% read-traffic skip). Writes are
// never skipped (workspace poisoned; GEMMs read stored zeros).
template<int MODE>
__global__ __launch_bounds__(256) void mask_cvt_tile(const float* __restrict__ in,
                                                     u16* __restrict__ out, int W) {
  const int r0 = blockIdx.y * 64;
  const int c0 = blockIdx.x * 64;
  const int re = r0 + 63, ce = c0 + 63;

  bool zero;
  if (MODE == 0) {
    int rmaxd = (r0 >= 2047) ? ((re <= 4093) ? (re - 2047) : 2046)
                             : ((re <= 2046) ? re : 2046);
    zero = (c0 > rmaxd);
  } else if (MODE == 1) {
    int rmaxd = (r0 >= 2047) ? ((re <= 4093) ? (re - 2047) : 2046)
                             : ((re <= 2046) ? re : 2046);
    int cmind = (c0 >= 2047) ? ((ce >= 4094) ? 0 : (c0 - 2047))
                             : ((ce >= 2047) ? 0 : c0);
    zero = (cmind > rmaxd);
  } else {
    int cmind = (c0 >= 2047) ? ((ce >= 4094) ? 0 : (c0 - 2047))
                             : ((ce >= 2047) ? 0 : c0);
    zero = (re <= cmind);
  }

  const int tr = threadIdx.x >> 4;
  const int tc = (threadIdx.x & 15) * 4;

  if (zero) {
    u16x4 z = {0, 0, 0, 0};
#pragma unroll
    for (int rr = 0; rr < 64; rr += 16)
      *(u16x4*)&out[(size_t)(r0 + tr + rr) * W + c0 + tc] = z;
    return;
  }

#pragma unroll
  for (int rr = 0; rr < 64; rr += 16) {
    int r = r0 + tr + rr;
    int rdeg = r % 2047;
    f32x4 v = *(const f32x4*)&in[(size_t)r * W + c0 + tc];
    u16x4 o;
#pragma unroll
    for (int e = 0; e < 4; ++e) {
      int c = c0 + tc + e;
      bool keep;
      if (MODE == 0)      keep = (c <= rdeg);
      else if (MODE == 1) keep = ((c % 2047) <= rdeg);
      else                keep = (r > (c % 2047));
      o[e] = keep ? f2bf(v[e]) : (u16)0;
    }
    *(u16x4*)&out[(size_t)r * W + c0 + tc] = o;
  }
}

// ============ 256x256 8-phase pipelined GEMM (G1/G2, EPI=relu+store) ========
// Two-run masked skip + EXTRA final K-tile when r2end<K (covers the double
// wrap deg(4094)=0, deg(4095)=1 -- kept by every row; boundary zeros exact).
template<int MASKM>
__global__ __launch_bounds__(512, 2) void gemm256_kernel(
    const u16* __restrict__ A, const u16* __restrict__ Bw,
    const float* __restrict__ bias, u16* __restrict__ C,
    int M, int N, int K)
{
  __shared__ u16 ls[2][32768];   // per slot: A chunks [0,2048), B chunks [2048,4096)

  const int tid  = threadIdx.x;
  const int wid  = tid >> 6;
  const int lane = tid & 63;
  const int wm = wid >> 2, wn = wid & 3;
  const int l15 = lane & 15, lhi = lane >> 4;
  const int brow = blockIdx.y * 256;
  const int p = blockIdx.x;
  int cols[2];
  cols[0] = (p < 4) ? p : p + 4;
  cols[1] = (p < 4) ? 7 - p : 19 - p;

  const int arow_ = tid >> 3;                 // 0..63
  const int agsub = (tid & 7) ^ (arow_ & 7);  // pre-swizzled source sub-chunk
  size_t aB[4];
  aB[0] = (size_t)(brow +   0 + arow_) * K + agsub * 8;
  aB[1] = (size_t)(brow + 128 + arow_) * K + agsub * 8;
  aB[2] = (size_t)(brow +  64 + arow_) * K + agsub * 8;
  aB[3] = (size_t)(brow + 192 + arow_) * K + agsub * 8;
  const int aCh[4] = {0, 1024, 512, 1536};    // LDS chunk bases

#pragma unroll 1
  for (int t = 0; t < 2; ++t) {
    const int bcol = cols[t] * 256;

    int rmax;
    {
      int sC = bcol, e = bcol + 255;
      if (e <= 2046)       rmax = e;
      else if (sC <= 2046) rmax = 2046;
      else { int em = e - 2047; rmax = (em <= 2046) ? em : 2046; }
    }
    int r1end = ((rmax >> 6) + 1) << 6; if (r1end > K) r1end = K;
    int run2start, r2end;
    if (MASKM == 1) { run2start = r1end; r2end = r1end; }
    else {
      run2start = (1984 > r1end) ? 1984 : r1end;
      r2end = (((2047 + rmax) >> 6) + 1) << 6; if (r2end > K) r2end = K;
      if (r2end < run2start) r2end = run2start;
    }
    const int n1 = r1end >> 6;
    const int nt = n1 + ((r2end - run2start) >> 6);
    const int roff = run2start - r1end;
    // extra final tile for the k=4094/4095 double-wrap columns
    const int nte = nt + ((MASKM != 1 && r2end < K) ? 1 : 0);

    size_t bB[2][2];
#pragma unroll
    for (int u = 0; u < 2; ++u)
#pragma unroll
      for (int c = 0; c < 2; ++c)
        bB[u][c] = (size_t)(bcol + u * 128 + arow_ + 64 * c) * K + agsub * 8;

    floatx4 acc[8][4];
#pragma unroll
    for (int i = 0; i < 8; ++i)
#pragma unroll
      for (int j = 0; j < 4; ++j)
        acc[i][j] = (floatx4){0.f, 0.f, 0.f, 0.f};

#define K0F(j) (((j) >= nt) ? (K - 64) : (((j) << 6) + (((j) >= n1) ? roff : 0)))
#define ST_A(slot_, idx_, k0v) glds16(A + aB[idx_] + (k0v), (u16*)&ls[slot_][(aCh[idx_] + tid) * 8])
#define ST_B(slot_, u_, k0v) do { \
      glds16(Bw + bB[u_][0] + (k0v), (u16*)&ls[slot_][(2048 + (u_) * 1024 + tid) * 8]); \
      glds16(Bw + bB[u_][1] + (k0v), (u16*)&ls[slot_][(2048 + (u_) * 1024 + tid + 512) * 8]); \
    } while (0)

    ST_A(0, 0, K0F(0)); ST_A(0, 1, K0F(0));
    ST_B(0, 0, K0F(0)); ST_B(0, 1, K0F(0));
    ST_A(0, 2, K0F(0)); ST_A(0, 3, K0F(0));
    if (nte > 1) {
      const int k1p = K0F(1);
      ST_A(1, 0, k1p); ST_A(1, 1, k1p);
      asm volatile("s_waitcnt vmcnt(4)" ::: "memory");
    } else {
      asm volatile("s_waitcnt vmcnt(2)" ::: "memory");
    }
    __builtin_amdgcn_sched_barrier(0);
    __builtin_amdgcn_s_barrier();

#pragma unroll 1
    for (int i = 0; i < nte; ++i) {
      const int s = i & 1, o = s ^ 1;
      const u16* sA = &ls[s][0];
      const u16* sB = &ls[s][16384];
      const bool g1 = (i + 1 < nte), g2 = (i + 2 < nte);
      const int k1 = g1 ? K0F(i + 1) : 0;
      const int k2 = g2 ? K0F(i + 2) : 0;
      short8 af[4], bf0[4], bf1[4];

#define RD_A(q_, ks_) do { \
        _Pragma("unroll") \
        for (int mi = 0; mi < 4; ++mi) { \
          int row = wm * 128 + (q_) * 64 + mi * 16 + l15; \
          int ch = row * 8 + (((ks_) * 4 + lhi) ^ (row & 7)); \
          af[mi] = *(const short8*)&sA[ch * 8]; \
        } } while (0)
#define RD_B(ks_, dst_) do { \
        _Pragma("unroll") \
        for (int ni = 0; ni < 4; ++ni) { \
          int row = wn * 64 + ni * 16 + l15; \
          int ch = row * 8 + (((ks_) * 4 + lhi) ^ (row & 7)); \
          dst_[ni] = *(const short8*)&sB[ch * 8]; \
        } } while (0)
#define MFMA16(q_, bf_) do { \
        _Pragma("unroll") \
        for (int mi = 0; mi < 4; ++mi) \
          _Pragma("unroll") \
          for (int ni = 0; ni < 4; ++ni) \
            acc[(q_) * 4 + mi][ni] = __builtin_amdgcn_mfma_f32_16x16x32_bf16( \
                af[mi], bf_[ni], acc[(q_) * 4 + mi][ni], 0, 0, 0); \
        } while (0)

      // ---------- phase 0: q0 ks0 ----------
      RD_A(0, 0);
      RD_B(0, bf0);
      if (g1) ST_B(o, 0, k1);
      __builtin_amdgcn_s_barrier();
      asm volatile("s_waitcnt lgkmcnt(0)" ::: "memory");
      __builtin_amdgcn_sched_barrier(0);
      __builtin_amdgcn_s_setprio(1);
      MFMA16(0, bf0);
      __builtin_amdgcn_s_setprio(0);
      __builtin_amdgcn_s_barrier();

      // ---------- phase 1: q0 ks1 ----------
      RD_A(0, 1);
      RD_B(1, bf1);
      if (g1) ST_B(o, 1, k1);
      __builtin_amdgcn_s_barrier();
      asm volatile("s_waitcnt lgkmcnt(0)" ::: "memory");
      __builtin_amdgcn_sched_barrier(0);
      __builtin_amdgcn_s_setprio(1);
      MFMA16(0, bf1);
      __builtin_amdgcn_s_setprio(0);
      if (g1) {
        if (i == 0) asm volatile("s_waitcnt vmcnt(6)" ::: "memory");
        else        asm volatile("s_waitcnt vmcnt(5)" ::: "memory");
      } else {
        asm volatile("s_waitcnt vmcnt(0)" ::: "memory");
      }
      __builtin_amdgcn_sched_barrier(0);
      __builtin_amdgcn_s_barrier();

      // ---------- phase 2: q1 ks0 ----------
      RD_A(1, 0);
      if (g1) ST_A(o, 2, k1);
      if (g2) ST_A(s, 0, k2);
      __builtin_amdgcn_s_barrier();
      asm volatile("s_waitcnt lgkmcnt(0)" ::: "memory");
      __builtin_amdgcn_sched_barrier(0);
      __builtin_amdgcn_s_setprio(1);
      MFMA16(1, bf0);
      __builtin_amdgcn_s_setprio(0);
      __builtin_amdgcn_s_barrier();

      // ---------- phase 3: q1 ks1 ----------
      RD_A(1, 1);
      if (g1) ST_A(o, 3, k1);
      if (g2) ST_A(s, 1, k2);
      __builtin_amdgcn_s_barrier();
      asm volatile("s_waitcnt lgkmcnt(0)" ::: "memory");
      __builtin_amdgcn_sched_barrier(0);
      __builtin_amdgcn_s_setprio(1);
      MFMA16(1, bf1);
      __builtin_amdgcn_s_setprio(0);
      if (g1) {
        if (g2) asm volatile("s_waitcnt vmcnt(4)" ::: "memory");
        else    asm volatile("s_waitcnt vmcnt(2)" ::: "memory");
        __builtin_amdgcn_sched_barrier(0);
      }
      __builtin_amdgcn_s_barrier();
#undef RD_A
#undef RD_B
#undef MFMA16
    }

    // ---------- epilogue: C = relu(acc + bias) ----------
#pragma unroll
    for (int mi = 0; mi < 8; ++mi) {
      int row = brow + wm * 128 + (mi >> 2) * 64 + (mi & 3) * 16 + lhi * 4;
#pragma unroll
      for (int ni = 0; ni < 4; ++ni) {
        int col = bcol + wn * 64 + ni * 16 + l15;
        float bv = bias[col];
#pragma unroll
        for (int e = 0; e < 4; ++e) {
          float v = acc[mi][ni][e] + bv;
          v = fmaxf(v, 0.0f);
          C[(size_t)(row + e) * N + col] = f2bf(v);
        }
      }
    }
    __syncthreads();
#undef K0F
#undef ST_A
#undef ST_B
  }
}

// ============ G3: 128x256 2-phase pipelined GEMM + logprob epilogue =========
// 512 thr, 8 waves (2M x 4N), wave tile 64x64, BK=64, dbuf LDS 96KB.
// Per K-tile: 2 phases (ks0, ks1), each {8 ds_read || stage || barrier ||
// lgkmcnt(0) || setprio 16 MFMA || barrier}. All 6 stage units issued at ph0
// -> the ph1-end vmcnt(0) gate sits >=1.5 phases after last issue (~free).
// Same zero-conflict row&7 source-swizzle. Two-run skip + extra final tile
// (double-wrap fix). Pair {q, 7-q} balances (nt+1 ~ 74-75). Grid 4x64.
__global__ __launch_bounds__(512, 1) void gemm3p_kernel(
    const u16* __restrict__ A,      // h2: BB x HH
    const u16* __restrict__ Bw,     // w3m: DD x HH
    const float* __restrict__ bias, // b3
    const u16* __restrict__ vbf,    // value bf16: BB x DD
    float* __restrict__ outp,       // BB
    int M, int N, int K)
{
  __shared__ u16 ls[2][24576];      // per slot: A elems [0,8192), B [8192,24576)

  const int tid  = threadIdx.x;
  const int wid  = tid >> 6;
  const int lane = tid & 63;
  const int wm = wid >> 2, wn = wid & 3;
  const int l15 = lane & 15, lhi = lane >> 4;
  const int brow = blockIdx.y * 128;
  const int q = blockIdx.x;         // 0..3
  int sgs[2] = { q, 7 - q };

  // staging: A 2 chunks/thread (1024), B 4 chunks/thread (2048)
  size_t aOff[2];
#pragma unroll
  for (int u = 0; u < 2; ++u) {
    int ch = tid + 512 * u;
    int row = ch >> 3, sub = ch & 7;
    aOff[u] = (size_t)(brow + row) * K + (sub ^ (row & 7)) * 8;
  }
  int bRow[4], bSsub[4];
#pragma unroll
  for (int u = 0; u < 4; ++u) {
    int ch = tid + 512 * u;
    bRow[u] = ch >> 3;
    bSsub[u] = (ch & 7) ^ (bRow[u] & 7);
  }

#pragma unroll 1
  for (int t = 0; t < 2; ++t) {
    const int bcol = sgs[t] * 256;
    const int rmax = bcol + 254;    // keep k%2047 <= d-1; max d = bcol+255

    int r1end = ((rmax >> 6) + 1) << 6; if (r1end > K) r1end = K;
    int run2start = (1984 > r1end) ? 1984 : r1end;
    int r2end = (((2047 + rmax) >> 6) + 1) << 6; if (r2end > K) r2end = K;
    if (r2end < run2start) r2end = run2start;
    const int n1 = r1end >> 6;
    const int nt = n1 + ((r2end - run2start) >> 6);
    const int roff = run2start - r1end;
    const int nte = nt + ((r2end < K) ? 1 : 0);   // double-wrap fix

    size_t bOff[4];
#pragma unroll
    for (int u = 0; u < 4; ++u)
      bOff[u] = (size_t)(bcol + bRow[u]) * K + bSsub[u] * 8;

    floatx4 acc[4][4];
#pragma unroll
    for (int i = 0; i < 4; ++i)
#pragma unroll
      for (int j = 0; j < 4; ++j)
        acc[i][j] = (floatx4){0.f, 0.f, 0.f, 0.f};

#define K0G(j) (((j) >= nt) ? (K - 64) : (((j) << 6) + (((j) >= n1) ? roff : 0)))
#define ST3(slot_, k0v) do { \
      glds16(A  + aOff[0] + (k0v), (u16*)&ls[slot_][tid * 8]); \
      glds16(A  + aOff[1] + (k0v), (u16*)&ls[slot_][(512 + tid) * 8]); \
      glds16(Bw + bOff[0] + (k0v), (u16*)&ls[slot_][(1024 + tid) * 8]); \
      glds16(Bw + bOff[1] + (k0v), (u16*)&ls[slot_][(1536 + tid) * 8]); \
      glds16(Bw + bOff[2] + (k0v), (u16*)&ls[slot_][(2048 + tid) * 8]); \
      glds16(Bw + bOff[3] + (k0v), (u16*)&ls[slot_][(2560 + tid) * 8]); \
    } while (0)

    // prologue: stage tile 0 -> slot 0
    ST3(0, K0G(0));
    asm volatile("s_waitcnt vmcnt(0)" ::: "memory");
    __builtin_amdgcn_sched_barrier(0);
    __builtin_amdgcn_s_barrier();

#pragma unroll 1
    for (int i = 0; i < nte; ++i) {
      const int s = i & 1, o = s ^ 1;
      const u16* sA = &ls[s][0];
      const u16* sB = &ls[s][8192];
      const bool g1 = (i + 1 < nte);
      short8 af[4], bfv[4];

      // ---------- phase 0: ks0 ----------
#pragma unroll
      for (int mi = 0; mi < 4; ++mi) {
        int row = wm * 64 + mi * 16 + l15;
        af[mi] = *(const short8*)&sA[(row * 8 + (lhi ^ (row & 7))) * 8];
      }
#pragma unroll
      for (int ni = 0; ni < 4; ++ni) {
        int row = wn * 64 + ni * 16 + l15;
        bfv[ni] = *(const short8*)&sB[(row * 8 + (lhi ^ (row & 7))) * 8];
      }
      if (g1) ST3(o, K0G(i + 1));
      __builtin_amdgcn_s_barrier();
      asm volatile("s_waitcnt lgkmcnt(0)" ::: "memory");
      __builtin_amdgcn_sched_barrier(0);
      __builtin_amdgcn_s_setprio(1);
#pragma unroll
      for (int mi = 0; mi < 4; ++mi)
#pragma unroll
        for (int ni = 0; ni < 4; ++ni)
          acc[mi][ni] = __builtin_amdgcn_mfma_f32_16x16x32_bf16(af[mi], bfv[ni], acc[mi][ni], 0, 0, 0);
      __builtin_amdgcn_s_setprio(0);
      __builtin_amdgcn_s_barrier();

      // ---------- phase 1: ks1 ----------
#pragma unroll
      for (int mi = 0; mi < 4; ++mi) {
        int row = wm * 64 + mi * 16 + l15;
        af[mi] = *(const short8*)&sA[(row * 8 + ((4 + lhi) ^ (row & 7))) * 8];
      }
#pragma unroll
      for (int ni = 0; ni < 4; ++ni) {
        int row = wn * 64 + ni * 16 + l15;
        bfv[ni] = *(const short8*)&sB[(row * 8 + ((4 + lhi) ^ (row & 7))) * 8];
      }
      __builtin_amdgcn_s_barrier();
      asm volatile("s_waitcnt lgkmcnt(0)" ::: "memory");
      __builtin_amdgcn_sched_barrier(0);
      __builtin_amdgcn_s_setprio(1);
#pragma unroll
      for (int mi = 0; mi < 4; ++mi)
#pragma unroll
        for (int ni = 0; ni < 4; ++ni)
          acc[mi][ni] = __builtin_amdgcn_mfma_f32_16x16x32_bf16(af[mi], bfv[ni], acc[mi][ni], 0, 0, 0);
      __builtin_amdgcn_s_setprio(0);
      if (g1) {
        asm volatile("s_waitcnt vmcnt(0)" ::: "memory");   // issued 1.5 phases ago
        __builtin_amdgcn_sched_barrier(0);
      }
      __builtin_amdgcn_s_barrier();
    }
#undef K0G
#undef ST3

    // ---------- logprob epilogue ----------
#pragma unroll
    for (int mi = 0; mi < 4; ++mi) {
#pragma unroll
      for (int e = 0; e < 4; ++e) {
        int row = brow + wm * 64 + mi * 16 + lhi * 4 + e;
        float partial = 0.0f;
#pragma unroll
        for (int ni = 0; ni < 4; ++ni) {
          int col = bcol + wn * 64 + ni * 16 + l15;
          float l = acc[mi][ni][e] + bias[col];
          float v = bf2f(vbf[(size_t)row * N + col]);
          float sp = fmaxf(l, 0.0f) + __logf(1.0f + __expf(-fabsf(l)));
          partial += v * l - sp;
        }
#pragma unroll
        for (int off = 1; off < 16; off <<= 1)
          partial += __shfl_xor(partial, off, 64);
        if (l15 == 0) atomicAdd(&outp[row], partial);
      }
    }
  }
}

// ---------------- launcher ----------------
extern "C" void kernel_launch(void* const* d_in, const int* in_sizes, int n_in,
                              void* d_out, int out_size, void* d_ws, size_t ws_size,
                              hipStream_t stream) {
  const float* value = (const float*)d_in[0];
  const float* W1 = (const float*)d_in[1];
  const float* b1 = (const float*)d_in[2];
  const float* W2 = (const float*)d_in[3];
  const float* b2 = (const float*)d_in[4];
  const float* W3 = (const float*)d_in[5];
  const float* b3 = (const float*)d_in[6];
  float* out = (float*)d_out;

  char* ws = (char*)d_ws;
  u16* vbf = (u16*)(ws);                        // B*D bf16
  u16* w1m = (u16*)(ws + 33554432ULL);          // H*D bf16
  u16* w2m = (u16*)(ws + 50331648ULL);          // H*H bf16
  u16* w3m = (u16*)(ws + 83886080ULL);          // D*H bf16
  u16* h1  = (u16*)(ws + 100663296ULL);         // B*H bf16
  u16* h2  = (u16*)(ws + 167772160ULL);         // B*H bf16

  hipMemsetAsync(d_out, 0, (size_t)out_size * sizeof(float), stream);

  cvt_value_kernel<<<2048, 256, 0, stream>>>(value, vbf, (BB * DD) / 4);
  mask_cvt_tile<0><<<dim3(DD / 64, HH / 64), 256, 0, stream>>>(W1, w1m, DD);
  mask_cvt_tile<1><<<dim3(HH / 64, HH / 64), 256, 0, stream>>>(W2, w2m, HH);
  mask_cvt_tile<2><<<dim3(HH / 64, DD / 64), 256, 0, stream>>>(W3, w3m, HH);

  dim3 g12(8, BB / 256);
  gemm256_kernel<1><<<g12, 512, 0, stream>>>(vbf, w1m, b1, h1, BB, HH, DD);
  gemm256_kernel<2><<<g12, 512, 0, stream>>>(h1, w2m, b2, h2, BB, HH, HH);
  dim3 g3(4, BB / 128);
  gemm3p_kernel<<<g3, 512, 0, stream>>>(h2, w3m, b3, vbf, out, BB, DD, HH);
}

// Round 11
// 387.441 us; speedup vs baseline: 1.3471x; 1.0211x over previous
//
#include <hip/hip_runtime.h>
#include <hip/hip_bf16.h>
#include <cstdint>

typedef short short8 __attribute__((ext_vector_type(8)));
typedef float floatx4 __attribute__((ext_vector_type(4)));
typedef float f32x4 __attribute__((ext_vector_type(4)));
typedef unsigned short u16;
typedef unsigned short u16x4 __attribute__((ext_vector_type(4)));

#define BB 8192
#define DD 2048
#define HH 4096

static __device__ __forceinline__ u16 f2bf(float x) {
  __hip_bfloat16 h = __float2bfloat16(x);
  return __builtin_bit_cast(u16, h);
}

static __device__ __forceinline__ float bf2f(u16 x) {
  unsigned int u = ((unsigned int)x) << 16;
  return __builtin_bit_cast(float, u);
}

static __device__ __forceinline__ void glds16(const u16* g, u16* l) {
  __builtin_amdgcn_global_load_lds(
      (const __attribute__((address_space(1))) void*)g,
      (__attribute__((address_space(3))) void*)l, 16, 0, 0);
}

// ---------------- elementwise: value fp32 -> bf16 ----------------
__global__ void cvt_value_kernel(const float* __restrict__ in, u16* __restrict__ out, int n4) {
  int idx = blockIdx.x * blockDim.x + threadIdx.x;
  int stride = gridDim.x * blockDim.x;
  for (int i = idx; i < n4; i += stride) {
    f32x4 v = reinterpret_cast<const f32x4*>(in)[i];
    u16x4 o = { f2bf(v[0]), f2bf(v[1]), f2bf(v[2]), f2bf(v[3]) };
    reinterpret_cast<u16x4*>(out)[i] = o;
  }
}

// ---------------- tiled mask + cast weights (64x64 tiles) ----------------
template<int MODE>
__global__ __launch_bounds__(256) void mask_cvt_tile(const float* __restrict__ in,
                                                     u16* __restrict__ out, int W) {
  const int r0 = blockIdx.y * 64;
  const int c0 = blockIdx.x * 64;
  const int re = r0 + 63, ce = c0 + 63;

  bool zero;
  if (MODE == 0) {
    int rmaxd = (r0 >= 2047) ? ((re <= 4093) ? (re - 2047) : 2046)
                             : ((re <= 2046) ? re : 2046);
    zero = (c0 > rmaxd);
  } else if (MODE == 1) {
    int rmaxd = (r0 >= 2047) ? ((re <= 4093) ? (re - 2047) : 2046)
                             : ((re <= 2046) ? re : 2046);
    int cmind = (c0 >= 2047) ? ((ce >= 4094) ? 0 : (c0 - 2047))
                             : ((ce >= 2047) ? 0 : c0);
    zero = (cmind > rmaxd);
  } else {
    int cmind = (c0 >= 2047) ? ((ce >= 4094) ? 0 : (c0 - 2047))
                             : ((ce >= 2047) ? 0 : c0);
    zero = (re <= cmind);
  }

  const int tr = threadIdx.x >> 4;
  const int tc = (threadIdx.x & 15) * 4;

  if (zero) {
    u16x4 z = {0, 0, 0, 0};
#pragma unroll
    for (int rr = 0; rr < 64; rr += 16)
      *(u16x4*)&out[(size_t)(r0 + tr + rr) * W + c0 + tc] = z;
    return;
  }

#pragma unroll
  for (int rr = 0; rr < 64; rr += 16) {
    int r = r0 + tr + rr;
    int rdeg = r % 2047;
    f32x4 v = *(const f32x4*)&in[(size_t)r * W + c0 + tc];
    u16x4 o;
#pragma unroll
    for (int e = 0; e < 4; ++e) {
      int c = c0 + tc + e;
      bool keep;
      if (MODE == 0)      keep = (c <= rdeg);
      else if (MODE == 1) keep = ((c % 2047) <= rdeg);
      else                keep = (r > (c % 2047));
      o[e] = keep ? f2bf(v[e]) : (u16)0;
    }
    *(u16x4*)&out[(size_t)r * W + c0 + tc] = o;
  }
}

// ============ 256x256 single-barrier-per-tile pipelined GEMM (G1/G2) ========
// 512 thr, 8 waves (2Mx4N), wave tile 128x64, BK=64, dbuf 128KB.
// Per K-tile: stage tile i+1 -> slot o (8 glds), then 4 phases of
// {ds_read frags ; lgkmcnt(0)+sched_barrier ; setprio(1) 16 MFMA setprio(0)}
// with NO inter-phase barriers (all phases read slot s, written nowhere this
// tile), then vmcnt(0) (stages issued a full tile ago -> free) + ONE
// s_barrier. Cross-wave overlap: one wave's ds_reads run on the CU-wide LDS
// pipe while another wave's MFMAs drain the per-SIMD matrix pipe.
// Two-run masked skip + extra final K-tile (deg double-wrap at 4094). Exact.
template<int MASKM>
__global__ __launch_bounds__(512, 2) void gemm256_kernel(
    const u16* __restrict__ A, const u16* __restrict__ Bw,
    const float* __restrict__ bias, u16* __restrict__ C,
    int M, int N, int K)
{
  __shared__ u16 ls[2][32768];   // per slot: A chunks [0,2048), B chunks [2048,4096)

  const int tid  = threadIdx.x;
  const int wid  = tid >> 6;
  const int lane = tid & 63;
  const int wm = wid >> 2, wn = wid & 3;
  const int l15 = lane & 15, lhi = lane >> 4;
  const int brow = blockIdx.y * 256;
  const int p = blockIdx.x;
  int cols[2];
  cols[0] = (p < 4) ? p : p + 4;
  cols[1] = (p < 4) ? 7 - p : 19 - p;

  const int arow_ = tid >> 3;                 // 0..63
  const int agsub = (tid & 7) ^ (arow_ & 7);  // pre-swizzled source sub-chunk
  size_t aB[4];
  aB[0] = (size_t)(brow +   0 + arow_) * K + agsub * 8;
  aB[1] = (size_t)(brow + 128 + arow_) * K + agsub * 8;
  aB[2] = (size_t)(brow +  64 + arow_) * K + agsub * 8;
  aB[3] = (size_t)(brow + 192 + arow_) * K + agsub * 8;
  const int aCh[4] = {0, 1024, 512, 1536};    // LDS chunk bases

#pragma unroll 1
  for (int t = 0; t < 2; ++t) {
    const int bcol = cols[t] * 256;

    int rmax;
    {
      int sC = bcol, e = bcol + 255;
      if (e <= 2046)       rmax = e;
      else if (sC <= 2046) rmax = 2046;
      else { int em = e - 2047; rmax = (em <= 2046) ? em : 2046; }
    }
    int r1end = ((rmax >> 6) + 1) << 6; if (r1end > K) r1end = K;
    int run2start, r2end;
    if (MASKM == 1) { run2start = r1end; r2end = r1end; }
    else {
      run2start = (1984 > r1end) ? 1984 : r1end;
      r2end = (((2047 + rmax) >> 6) + 1) << 6; if (r2end > K) r2end = K;
      if (r2end < run2start) r2end = run2start;
    }
    const int n1 = r1end >> 6;
    const int nt = n1 + ((r2end - run2start) >> 6);
    const int roff = run2start - r1end;
    const int nte = nt + ((MASKM != 1 && r2end < K) ? 1 : 0);

    size_t bB[2][2];
#pragma unroll
    for (int u = 0; u < 2; ++u)
#pragma unroll
      for (int c = 0; c < 2; ++c)
        bB[u][c] = (size_t)(bcol + u * 128 + arow_ + 64 * c) * K + agsub * 8;

    floatx4 acc[8][4];
#pragma unroll
    for (int i = 0; i < 8; ++i)
#pragma unroll
      for (int j = 0; j < 4; ++j)
        acc[i][j] = (floatx4){0.f, 0.f, 0.f, 0.f};

#define K0F(j) (((j) >= nt) ? (K - 64) : (((j) << 6) + (((j) >= n1) ? roff : 0)))
#define ST_A(slot_, idx_, k0v) glds16(A + aB[idx_] + (k0v), (u16*)&ls[slot_][(aCh[idx_] + tid) * 8])
#define ST_B(slot_, u_, k0v) do { \
      glds16(Bw + bB[u_][0] + (k0v), (u16*)&ls[slot_][(2048 + (u_) * 1024 + tid) * 8]); \
      glds16(Bw + bB[u_][1] + (k0v), (u16*)&ls[slot_][(2048 + (u_) * 1024 + tid + 512) * 8]); \
    } while (0)
#define ST_TILE(slot_, k0v) do { \
      ST_A(slot_, 0, k0v); ST_A(slot_, 1, k0v); ST_A(slot_, 2, k0v); ST_A(slot_, 3, k0v); \
      ST_B(slot_, 0, k0v); ST_B(slot_, 1, k0v); \
    } while (0)

    // prologue: stage tile 0 -> slot 0
    {
      const int k00 = K0F(0);
      ST_TILE(0, k00);
    }
    asm volatile("s_waitcnt vmcnt(0)" ::: "memory");
    __builtin_amdgcn_sched_barrier(0);
    __builtin_amdgcn_s_barrier();
    __builtin_amdgcn_sched_barrier(0);

#pragma unroll 1
    for (int i = 0; i < nte; ++i) {
      const int s = i & 1, o = s ^ 1;
      const u16* sA = &ls[s][0];
      const u16* sB = &ls[s][16384];
      const bool g1 = (i + 1 < nte);
      short8 af[4], bf0[4], bf1[4];

      if (g1) {
        const int k1 = K0F(i + 1);
        ST_TILE(o, k1);
      }

#define RD_A(q_, ks_) do { \
        _Pragma("unroll") \
        for (int mi = 0; mi < 4; ++mi) { \
          int row = wm * 128 + (q_) * 64 + mi * 16 + l15; \
          int ch = row * 8 + (((ks_) * 4 + lhi) ^ (row & 7)); \
          af[mi] = *(const short8*)&sA[ch * 8]; \
        } } while (0)
#define RD_B(ks_, dst_) do { \
        _Pragma("unroll") \
        for (int ni = 0; ni < 4; ++ni) { \
          int row = wn * 64 + ni * 16 + l15; \
          int ch = row * 8 + (((ks_) * 4 + lhi) ^ (row & 7)); \
          dst_[ni] = *(const short8*)&sB[ch * 8]; \
        } } while (0)
#define MFMA16(q_, bf_) do { \
        _Pragma("unroll") \
        for (int mi = 0; mi < 4; ++mi) \
          _Pragma("unroll") \
          for (int ni = 0; ni < 4; ++ni) \
            acc[(q_) * 4 + mi][ni] = __builtin_amdgcn_mfma_f32_16x16x32_bf16( \
                af[mi], bf_[ni], acc[(q_) * 4 + mi][ni], 0, 0, 0); \
        } while (0)

      // phase 0: q0 ks0
      RD_A(0, 0);
      RD_B(0, bf0);
      asm volatile("s_waitcnt lgkmcnt(0)" ::: "memory");
      __builtin_amdgcn_sched_barrier(0);
      __builtin_amdgcn_s_setprio(1);
      MFMA16(0, bf0);
      __builtin_amdgcn_s_setprio(0);

      // phase 1: q0 ks1
      RD_A(0, 1);
      RD_B(1, bf1);
      asm volatile("s_waitcnt lgkmcnt(0)" ::: "memory");
      __builtin_amdgcn_sched_barrier(0);
      __builtin_amdgcn_s_setprio(1);
      MFMA16(0, bf1);
      __builtin_amdgcn_s_setprio(0);

      // phase 2: q1 ks0
      RD_A(1, 0);
      asm volatile("s_waitcnt lgkmcnt(0)" ::: "memory");
      __builtin_amdgcn_sched_barrier(0);
      __builtin_amdgcn_s_setprio(1);
      MFMA16(1, bf0);
      __builtin_amdgcn_s_setprio(0);

      // phase 3: q1 ks1
      RD_A(1, 1);
      asm volatile("s_waitcnt lgkmcnt(0)" ::: "memory");
      __builtin_amdgcn_sched_barrier(0);
      __builtin_amdgcn_s_setprio(1);
      MFMA16(1, bf1);
      __builtin_amdgcn_s_setprio(0);

      // tile boundary: stages for i+1 issued a full tile ago
      asm volatile("s_waitcnt vmcnt(0)" ::: "memory");
      __builtin_amdgcn_sched_barrier(0);
      __builtin_amdgcn_s_barrier();
      __builtin_amdgcn_sched_barrier(0);
#undef RD_A
#undef RD_B
#undef MFMA16
    }

    // ---------- epilogue: C = relu(acc + bias) ----------
#pragma unroll
    for (int mi = 0; mi < 8; ++mi) {
      int row = brow + wm * 128 + (mi >> 2) * 64 + (mi & 3) * 16 + lhi * 4;
#pragma unroll
      for (int ni = 0; ni < 4; ++ni) {
        int col = bcol + wn * 64 + ni * 16 + l15;
        float bv = bias[col];
#pragma unroll
        for (int e = 0; e < 4; ++e) {
          float v = acc[mi][ni][e] + bv;
          v = fmaxf(v, 0.0f);
          C[(size_t)(row + e) * N + col] = f2bf(v);
        }
      }
    }
    __syncthreads();
#undef K0F
#undef ST_A
#undef ST_B
#undef ST_TILE
  }
}

// ============ G3: 128x256 single-barrier 2-phase GEMM + logprob epilogue ====
__global__ __launch_bounds__(512, 1) void gemm3p_kernel(
    const u16* __restrict__ A,      // h2: BB x HH
    const u16* __restrict__ Bw,     // w3m: DD x HH
    const float* __restrict__ bias, // b3
    const u16* __restrict__ vbf,    // value bf16: BB x DD
    float* __restrict__ outp,       // BB
    int M, int N, int K)
{
  __shared__ u16 ls[2][24576];      // per slot: A elems [0,8192), B [8192,24576)

  const int tid  = threadIdx.x;
  const int wid  = tid >> 6;
  const int lane = tid & 63;
  const int wm = wid >> 2, wn = wid & 3;
  const int l15 = lane & 15, lhi = lane >> 4;
  const int brow = blockIdx.y * 128;
  const int q = blockIdx.x;         // 0..3
  int sgs[2] = { q, 7 - q };

  size_t aOff[2];
#pragma unroll
  for (int u = 0; u < 2; ++u) {
    int ch = tid + 512 * u;
    int row = ch >> 3, sub = ch & 7;
    aOff[u] = (size_t)(brow + row) * K + (sub ^ (row & 7)) * 8;
  }
  int bRow[4], bSsub[4];
#pragma unroll
  for (int u = 0; u < 4; ++u) {
    int ch = tid + 512 * u;
    bRow[u] = ch >> 3;
    bSsub[u] = (ch & 7) ^ (bRow[u] & 7);
  }

#pragma unroll 1
  for (int t = 0; t < 2; ++t) {
    const int bcol = sgs[t] * 256;
    const int rmax = bcol + 254;

    int r1end = ((rmax >> 6) + 1) << 6; if (r1end > K) r1end = K;
    int run2start = (1984 > r1end) ? 1984 : r1end;
    int r2end = (((2047 + rmax) >> 6) + 1) << 6; if (r2end > K) r2end = K;
    if (r2end < run2start) r2end = run2start;
    const int n1 = r1end >> 6;
    const int nt = n1 + ((r2end - run2start) >> 6);
    const int roff = run2start - r1end;
    const int nte = nt + ((r2end < K) ? 1 : 0);

    size_t bOff[4];
#pragma unroll
    for (int u = 0; u < 4; ++u)
      bOff[u] = (size_t)(bcol + bRow[u]) * K + bSsub[u] * 8;

    floatx4 acc[4][4];
#pragma unroll
    for (int i = 0; i < 4; ++i)
#pragma unroll
      for (int j = 0; j < 4; ++j)
        acc[i][j] = (floatx4){0.f, 0.f, 0.f, 0.f};

#define K0G(j) (((j) >= nt) ? (K - 64) : (((j) << 6) + (((j) >= n1) ? roff : 0)))
#define ST3(slot_, k0v) do { \
      glds16(A  + aOff[0] + (k0v), (u16*)&ls[slot_][tid * 8]); \
      glds16(A  + aOff[1] + (k0v), (u16*)&ls[slot_][(512 + tid) * 8]); \
      glds16(Bw + bOff[0] + (k0v), (u16*)&ls[slot_][(1024 + tid) * 8]); \
      glds16(Bw + bOff[1] + (k0v), (u16*)&ls[slot_][(1536 + tid) * 8]); \
      glds16(Bw + bOff[2] + (k0v), (u16*)&ls[slot_][(2048 + tid) * 8]); \
      glds16(Bw + bOff[3] + (k0v), (u16*)&ls[slot_][(2560 + tid) * 8]); \
    } while (0)

    ST3(0, K0G(0));
    asm volatile("s_waitcnt vmcnt(0)" ::: "memory");
    __builtin_amdgcn_sched_barrier(0);
    __builtin_amdgcn_s_barrier();
    __builtin_amdgcn_sched_barrier(0);

#pragma unroll 1
    for (int i = 0; i < nte; ++i) {
      const int s = i & 1, o = s ^ 1;
      const u16* sA = &ls[s][0];
      const u16* sB = &ls[s][8192];
      const bool g1 = (i + 1 < nte);
      short8 af[4], bfv[4];

      if (g1) ST3(o, K0G(i + 1));

      // phase 0: ks0
#pragma unroll
      for (int mi = 0; mi < 4; ++mi) {
        int row = wm * 64 + mi * 16 + l15;
        af[mi] = *(const short8*)&sA[(row * 8 + (lhi ^ (row & 7))) * 8];
      }
#pragma unroll
      for (int ni = 0; ni < 4; ++ni) {
        int row = wn * 64 + ni * 16 + l15;
        bfv[ni] = *(const short8*)&sB[(row * 8 + (lhi ^ (row & 7))) * 8];
      }
      asm volatile("s_waitcnt lgkmcnt(0)" ::: "memory");
      __builtin_amdgcn_sched_barrier(0);
      __builtin_amdgcn_s_setprio(1);
#pragma unroll
      for (int mi = 0; mi < 4; ++mi)
#pragma unroll
        for (int ni = 0; ni < 4; ++ni)
          acc[mi][ni] = __builtin_amdgcn_mfma_f32_16x16x32_bf16(af[mi], bfv[ni], acc[mi][ni], 0, 0, 0);
      __builtin_amdgcn_s_setprio(0);

      // phase 1: ks1
#pragma unroll
      for (int mi = 0; mi < 4; ++mi) {
        int row = wm * 64 + mi * 16 + l15;
        af[mi] = *(const short8*)&sA[(row * 8 + ((4 + lhi) ^ (row & 7))) * 8];
      }
#pragma unroll
      for (int ni = 0; ni < 4; ++ni) {
        int row = wn * 64 + ni * 16 + l15;
        bfv[ni] = *(const short8*)&sB[(row * 8 + ((4 + lhi) ^ (row & 7))) * 8];
      }
      asm volatile("s_waitcnt lgkmcnt(0)" ::: "memory");
      __builtin_amdgcn_sched_barrier(0);
      __builtin_amdgcn_s_setprio(1);
#pragma unroll
      for (int mi = 0; mi < 4; ++mi)
#pragma unroll
        for (int ni = 0; ni < 4; ++ni)
          acc[mi][ni] = __builtin_amdgcn_mfma_f32_16x16x32_bf16(af[mi], bfv[ni], acc[mi][ni], 0, 0, 0);
      __builtin_amdgcn_s_setprio(0);

      asm volatile("s_waitcnt vmcnt(0)" ::: "memory");
      __builtin_amdgcn_sched_barrier(0);
      __builtin_amdgcn_s_barrier();
      __builtin_amdgcn_sched_barrier(0);
    }
#undef K0G
#undef ST3

    // ---------- logprob epilogue ----------
#pragma unroll
    for (int mi = 0; mi < 4; ++mi) {
#pragma unroll
      for (int e = 0; e < 4; ++e) {
        int row = brow + wm * 64 + mi * 16 + lhi * 4 + e;
        float partial = 0.0f;
#pragma unroll
        for (int ni = 0; ni < 4; ++ni) {
          int col = bcol + wn * 64 + ni * 16 + l15;
          float l = acc[mi][ni][e] + bias[col];
          float v = bf2f(vbf[(size_t)row * N + col]);
          float sp = fmaxf(l, 0.0f) + __logf(1.0f + __expf(-fabsf(l)));
          partial += v * l - sp;
        }
#pragma unroll
        for (int off = 1; off < 16; off <<= 1)
          partial += __shfl_xor(partial, off, 64);
        if (l15 == 0) atomicAdd(&outp[row], partial);
      }
    }
  }
}

// ---------------- launcher ----------------
extern "C" void kernel_launch(void* const* d_in, const int* in_sizes, int n_in,
                              void* d_out, int out_size, void* d_ws, size_t ws_size,
                              hipStream_t stream) {
  const float* value = (const float*)d_in[0];
  const float* W1 = (const float*)d_in[1];
  const float* b1 = (const float*)d_in[2];
  const float* W2 = (const float*)d_in[3];
  const float* b2 = (const float*)d_in[4];
  const float* W3 = (const float*)d_in[5];
  const float* b3 = (const float*)d_in[6];
  float* out = (float*)d_out;

  char* ws = (char*)d_ws;
  u16* vbf = (u16*)(ws);                        // B*D bf16
  u16* w1m = (u16*)(ws + 33554432ULL);          // H*D bf16
  u16* w2m = (u16*)(ws + 50331648ULL);          // H*H bf16
  u16* w3m = (u16*)(ws + 83886080ULL);          // D*H bf16
  u16* h1  = (u16*)(ws + 100663296ULL);         // B*H bf16
  u16* h2  = (u16*)(ws + 167772160ULL);         // B*H bf16

  hipMemsetAsync(d_out, 0, (size_t)out_size * sizeof(float), stream);

  cvt_value_kernel<<<2048, 256, 0, stream>>>(value, vbf, (BB * DD) / 4);
  mask_cvt_tile<0><<<dim3(DD / 64, HH / 64), 256, 0, stream>>>(W1, w1m, DD);
  mask_cvt_tile<1><<<dim3(HH / 64, HH / 64), 256, 0, stream>>>(W2, w2m, HH);
  mask_cvt_tile<2><<<dim3(HH / 64, DD / 64), 256, 0, stream>>>(W3, w3m, HH);

  dim3 g12(8, BB / 256);
  gemm256_kernel<1><<<g12, 512, 0, stream>>>(vbf, w1m, b1, h1, BB, HH, DD);
  gemm256_kernel<2><<<g12, 512, 0, stream>>>(h1, w2m, b2, h2, BB, HH, HH);
  dim3 g3(4, BB / 128);
  gemm3p_kernel<<<g3, 512, 0, stream>>>(h2, w3m, b3, vbf, out, BB, DD, HH);
}

// Round 12
// 357.117 us; speedup vs baseline: 1.4615x; 1.0849x over previous
//
#include <hip/hip_runtime.h>
#include <hip/hip_bf16.h>
#include <cstdint>

typedef short short8 __attribute__((ext_vector_type(8)));
typedef float floatx4 __attribute__((ext_vector_type(4)));
typedef float f32x4 __attribute__((ext_vector_type(4)));
typedef unsigned short u16;
typedef unsigned short u16x4 __attribute__((ext_vector_type(4)));

#define BB 8192
#define DD 2048
#define HH 4096

static __device__ __forceinline__ u16 f2bf(float x) {
  __hip_bfloat16 h = __float2bfloat16(x);
  return __builtin_bit_cast(u16, h);
}

static __device__ __forceinline__ float bf2f(u16 x) {
  unsigned int u = ((unsigned int)x) << 16;
  return __builtin_bit_cast(float, u);
}

static __device__ __forceinline__ void glds16(const u16* g, u16* l) {
  __builtin_amdgcn_global_load_lds(
      (const __attribute__((address_space(1))) void*)g,
      (__attribute__((address_space(3))) void*)l, 16, 0, 0);
}

// ---------------- elementwise: value fp32 -> bf16 ----------------
__global__ void cvt_value_kernel(const float* __restrict__ in, u16* __restrict__ out, int n4) {
  int idx = blockIdx.x * blockDim.x + threadIdx.x;
  int stride = gridDim.x * blockDim.x;
  for (int i = idx; i < n4; i += stride) {
    f32x4 v = reinterpret_cast<const f32x4*>(in)[i];
    u16x4 o = { f2bf(v[0]), f2bf(v[1]), f2bf(v[2]), f2bf(v[3]) };
    reinterpret_cast<u16x4*>(out)[i] = o;
  }
}

// ---------------- tiled mask + cast weights (64x64 tiles) ----------------
template<int MODE>
__global__ __launch_bounds__(256) void mask_cvt_tile(const float* __restrict__ in,
                                                     u16* __restrict__ out, int W) {
  const int r0 = blockIdx.y * 64;
  const int c0 = blockIdx.x * 64;
  const int re = r0 + 63, ce = c0 + 63;

  bool zero;
  if (MODE == 0) {
    int rmaxd = (r0 >= 2047) ? ((re <= 4093) ? (re - 2047) : 2046)
                             : ((re <= 2046) ? re : 2046);
    zero = (c0 > rmaxd);
  } else if (MODE == 1) {
    int rmaxd = (r0 >= 2047) ? ((re <= 4093) ? (re - 2047) : 2046)
                             : ((re <= 2046) ? re : 2046);
    int cmind = (c0 >= 2047) ? ((ce >= 4094) ? 0 : (c0 - 2047))
                             : ((ce >= 2047) ? 0 : c0);
    zero = (cmind > rmaxd);
  } else {
    int cmind = (c0 >= 2047) ? ((ce >= 4094) ? 0 : (c0 - 2047))
                             : ((ce >= 2047) ? 0 : c0);
    zero = (re <= cmind);
  }

  const int tr = threadIdx.x >> 4;
  const int tc = (threadIdx.x & 15) * 4;

  if (zero) {
    u16x4 z = {0, 0, 0, 0};
#pragma unroll
    for (int rr = 0; rr < 64; rr += 16)
      *(u16x4*)&out[(size_t)(r0 + tr + rr) * W + c0 + tc] = z;
    return;
  }

#pragma unroll
  for (int rr = 0; rr < 64; rr += 16) {
    int r = r0 + tr + rr;
    int rdeg = r % 2047;
    f32x4 v = *(const f32x4*)&in[(size_t)r * W + c0 + tc];
    u16x4 o;
#pragma unroll
    for (int e = 0; e < 4; ++e) {
      int c = c0 + tc + e;
      bool keep;
      if (MODE == 0)      keep = (c <= rdeg);
      else if (MODE == 1) keep = ((c % 2047) <= rdeg);
      else                keep = (r > (c % 2047));
      o[e] = keep ? f2bf(v[e]) : (u16)0;
    }
    *(u16x4*)&out[(size_t)r * W + c0 + tc] = o;
  }
}

// ============ 256x256 single-barrier-per-tile pipelined GEMM (G1/G2) ========
// XCD-aware swizzle (Option B): hw wg -> (x, y) with XCD (= wg%8) owning a
// 4-row-group across ALL 8 col-pairs. The 32 blocks on one XCD then share
// only 4 A-row-slices (A k-tiles L2-hit x8) instead of 32 distinct ones --
// cuts the dominant A staging traffic from L3 ~2.7x. B-tiles shared 4x.
template<int MASKM>
__global__ __launch_bounds__(512, 2) void gemm256_kernel(
    const u16* __restrict__ A, const u16* __restrict__ Bw,
    const float* __restrict__ bias, u16* __restrict__ C,
    int M, int N, int K)
{
  __shared__ u16 ls[2][32768];   // per slot: A chunks [0,2048), B chunks [2048,4096)

  const int tid  = threadIdx.x;
  const int wid  = tid >> 6;
  const int lane = tid & 63;
  const int wm = wid >> 2, wn = wid & 3;
  const int l15 = lane & 15, lhi = lane >> 4;

  // XCD=y-group swizzle: c = XCD, j = slot; y = 4c + (j&3), x = j>>2
  const int wg = blockIdx.x;
  const int xcd = wg & 7, j = wg >> 3;
  const int yb = (xcd << 2) | (j & 3);
  const int p  = j >> 2;
  const int brow = yb * 256;
  int cols[2];
  cols[0] = (p < 4) ? p : p + 4;
  cols[1] = (p < 4) ? 7 - p : 19 - p;

  const int arow_ = tid >> 3;                 // 0..63
  const int agsub = (tid & 7) ^ (arow_ & 7);  // pre-swizzled source sub-chunk
  size_t aB[4];
  aB[0] = (size_t)(brow +   0 + arow_) * K + agsub * 8;
  aB[1] = (size_t)(brow + 128 + arow_) * K + agsub * 8;
  aB[2] = (size_t)(brow +  64 + arow_) * K + agsub * 8;
  aB[3] = (size_t)(brow + 192 + arow_) * K + agsub * 8;
  const int aCh[4] = {0, 1024, 512, 1536};    // LDS chunk bases

#pragma unroll 1
  for (int t = 0; t < 2; ++t) {
    const int bcol = cols[t] * 256;

    int rmax;
    {
      int sC = bcol, e = bcol + 255;
      if (e <= 2046)       rmax = e;
      else if (sC <= 2046) rmax = 2046;
      else { int em = e - 2047; rmax = (em <= 2046) ? em : 2046; }
    }
    int r1end = ((rmax >> 6) + 1) << 6; if (r1end > K) r1end = K;
    int run2start, r2end;
    if (MASKM == 1) { run2start = r1end; r2end = r1end; }
    else {
      run2start = (1984 > r1end) ? 1984 : r1end;
      r2end = (((2047 + rmax) >> 6) + 1) << 6; if (r2end > K) r2end = K;
      if (r2end < run2start) r2end = run2start;
    }
    const int n1 = r1end >> 6;
    const int nt = n1 + ((r2end - run2start) >> 6);
    const int roff = run2start - r1end;
    const int nte = nt + ((MASKM != 1 && r2end < K) ? 1 : 0);

    size_t bB[2][2];
#pragma unroll
    for (int u = 0; u < 2; ++u)
#pragma unroll
      for (int c = 0; c < 2; ++c)
        bB[u][c] = (size_t)(bcol + u * 128 + arow_ + 64 * c) * K + agsub * 8;

    floatx4 acc[8][4];
#pragma unroll
    for (int i = 0; i < 8; ++i)
#pragma unroll
      for (int jj = 0; jj < 4; ++jj)
        acc[i][jj] = (floatx4){0.f, 0.f, 0.f, 0.f};

#define K0F(jx) (((jx) >= nt) ? (K - 64) : (((jx) << 6) + (((jx) >= n1) ? roff : 0)))
#define ST_A(slot_, idx_, k0v) glds16(A + aB[idx_] + (k0v), (u16*)&ls[slot_][(aCh[idx_] + tid) * 8])
#define ST_B(slot_, u_, k0v) do { \
      glds16(Bw + bB[u_][0] + (k0v), (u16*)&ls[slot_][(2048 + (u_) * 1024 + tid) * 8]); \
      glds16(Bw + bB[u_][1] + (k0v), (u16*)&ls[slot_][(2048 + (u_) * 1024 + tid + 512) * 8]); \
    } while (0)
#define ST_TILE(slot_, k0v) do { \
      ST_A(slot_, 0, k0v); ST_A(slot_, 1, k0v); ST_A(slot_, 2, k0v); ST_A(slot_, 3, k0v); \
      ST_B(slot_, 0, k0v); ST_B(slot_, 1, k0v); \
    } while (0)

    // prologue: stage tile 0 -> slot 0
    {
      const int k00 = K0F(0);
      ST_TILE(0, k00);
    }
    asm volatile("s_waitcnt vmcnt(0)" ::: "memory");
    __builtin_amdgcn_sched_barrier(0);
    __builtin_amdgcn_s_barrier();
    __builtin_amdgcn_sched_barrier(0);

#pragma unroll 1
    for (int i = 0; i < nte; ++i) {
      const int s = i & 1, o = s ^ 1;
      const u16* sA = &ls[s][0];
      const u16* sB = &ls[s][16384];
      const bool g1 = (i + 1 < nte);
      short8 af[4], bf0[4], bf1[4];

      if (g1) {
        const int k1 = K0F(i + 1);
        ST_TILE(o, k1);
      }

#define RD_A(q_, ks_) do { \
        _Pragma("unroll") \
        for (int mi = 0; mi < 4; ++mi) { \
          int row = wm * 128 + (q_) * 64 + mi * 16 + l15; \
          int ch = row * 8 + (((ks_) * 4 + lhi) ^ (row & 7)); \
          af[mi] = *(const short8*)&sA[ch * 8]; \
        } } while (0)
#define RD_B(ks_, dst_) do { \
        _Pragma("unroll") \
        for (int ni = 0; ni < 4; ++ni) { \
          int row = wn * 64 + ni * 16 + l15; \
          int ch = row * 8 + (((ks_) * 4 + lhi) ^ (row & 7)); \
          dst_[ni] = *(const short8*)&sB[ch * 8]; \
        } } while (0)
#define MFMA16(q_, bf_) do { \
        _Pragma("unroll") \
        for (int mi = 0; mi < 4; ++mi) \
          _Pragma("unroll") \
          for (int ni = 0; ni < 4; ++ni) \
            acc[(q_) * 4 + mi][ni] = __builtin_amdgcn_mfma_f32_16x16x32_bf16( \
                af[mi], bf_[ni], acc[(q_) * 4 + mi][ni], 0, 0, 0); \
        } while (0)

      // phase 0: q0 ks0
      RD_A(0, 0);
      RD_B(0, bf0);
      asm volatile("s_waitcnt lgkmcnt(0)" ::: "memory");
      __builtin_amdgcn_sched_barrier(0);
      __builtin_amdgcn_s_setprio(1);
      MFMA16(0, bf0);
      __builtin_amdgcn_s_setprio(0);

      // phase 1: q0 ks1
      RD_A(0, 1);
      RD_B(1, bf1);
      asm volatile("s_waitcnt lgkmcnt(0)" ::: "memory");
      __builtin_amdgcn_sched_barrier(0);
      __builtin_amdgcn_s_setprio(1);
      MFMA16(0, bf1);
      __builtin_amdgcn_s_setprio(0);

      // phase 2: q1 ks0
      RD_A(1, 0);
      asm volatile("s_waitcnt lgkmcnt(0)" ::: "memory");
      __builtin_amdgcn_sched_barrier(0);
      __builtin_amdgcn_s_setprio(1);
      MFMA16(1, bf0);
      __builtin_amdgcn_s_setprio(0);

      // phase 3: q1 ks1
      RD_A(1, 1);
      asm volatile("s_waitcnt lgkmcnt(0)" ::: "memory");
      __builtin_amdgcn_sched_barrier(0);
      __builtin_amdgcn_s_setprio(1);
      MFMA16(1, bf1);
      __builtin_amdgcn_s_setprio(0);

      // tile boundary: stages for i+1 issued a full tile ago
      asm volatile("s_waitcnt vmcnt(0)" ::: "memory");
      __builtin_amdgcn_sched_barrier(0);
      __builtin_amdgcn_s_barrier();
      __builtin_amdgcn_sched_barrier(0);
#undef RD_A
#undef RD_B
#undef MFMA16
    }

    // ---------- epilogue: C = relu(acc + bias) ----------
#pragma unroll
    for (int mi = 0; mi < 8; ++mi) {
      int row = brow + wm * 128 + (mi >> 2) * 64 + (mi & 3) * 16 + lhi * 4;
#pragma unroll
      for (int ni = 0; ni < 4; ++ni) {
        int col = bcol + wn * 64 + ni * 16 + l15;
        float bv = bias[col];
#pragma unroll
        for (int e = 0; e < 4; ++e) {
          float v = acc[mi][ni][e] + bv;
          v = fmaxf(v, 0.0f);
          C[(size_t)(row + e) * N + col] = f2bf(v);
        }
      }
    }
    __syncthreads();
#undef K0F
#undef ST_A
#undef ST_B
#undef ST_TILE
  }
}

// ============ G3: 128x256 single-barrier 2-phase GEMM + logprob epilogue ====
__global__ __launch_bounds__(512, 1) void gemm3p_kernel(
    const u16* __restrict__ A,      // h2: BB x HH
    const u16* __restrict__ Bw,     // w3m: DD x HH
    const float* __restrict__ bias, // b3
    const u16* __restrict__ vbf,    // value bf16: BB x DD
    float* __restrict__ outp,       // BB
    int M, int N, int K)
{
  __shared__ u16 ls[2][24576];      // per slot: A elems [0,8192), B [8192,24576)

  const int tid  = threadIdx.x;
  const int wid  = tid >> 6;
  const int lane = tid & 63;
  const int wm = wid >> 2, wn = wid & 3;
  const int l15 = lane & 15, lhi = lane >> 4;

  // XCD=y-group swizzle: y = 8c + (j&7), x = j>>3
  const int wg = blockIdx.x;
  const int xcd = wg & 7, j = wg >> 3;
  const int yb = (xcd << 3) | (j & 7);
  const int q  = j >> 3;            // 0..3
  const int brow = yb * 128;
  int sgs[2] = { q, 7 - q };

  size_t aOff[2];
#pragma unroll
  for (int u = 0; u < 2; ++u) {
    int ch = tid + 512 * u;
    int row = ch >> 3, sub = ch & 7;
    aOff[u] = (size_t)(brow + row) * K + (sub ^ (row & 7)) * 8;
  }
  int bRow[4], bSsub[4];
#pragma unroll
  for (int u = 0; u < 4; ++u) {
    int ch = tid + 512 * u;
    bRow[u] = ch >> 3;
    bSsub[u] = (ch & 7) ^ (bRow[u] & 7);
  }

#pragma unroll 1
  for (int t = 0; t < 2; ++t) {
    const int bcol = sgs[t] * 256;
    const int rmax = bcol + 254;

    int r1end = ((rmax >> 6) + 1) << 6; if (r1end > K) r1end = K;
    int run2start = (1984 > r1end) ? 1984 : r1end;
    int r2end = (((2047 + rmax) >> 6) + 1) << 6; if (r2end > K) r2end = K;
    if (r2end < run2start) r2end = run2start;
    const int n1 = r1end >> 6;
    const int nt = n1 + ((r2end - run2start) >> 6);
    const int roff = run2start - r1end;
    const int nte = nt + ((r2end < K) ? 1 : 0);

    size_t bOff[4];
#pragma unroll
    for (int u = 0; u < 4; ++u)
      bOff[u] = (size_t)(bcol + bRow[u]) * K + bSsub[u] * 8;

    floatx4 acc[4][4];
#pragma unroll
    for (int i = 0; i < 4; ++i)
#pragma unroll
      for (int jj = 0; jj < 4; ++jj)
        acc[i][jj] = (floatx4){0.f, 0.f, 0.f, 0.f};

#define K0G(jx) (((jx) >= nt) ? (K - 64) : (((jx) << 6) + (((jx) >= n1) ? roff : 0)))
#define ST3(slot_, k0v) do { \
      glds16(A  + aOff[0] + (k0v), (u16*)&ls[slot_][tid * 8]); \
      glds16(A  + aOff[1] + (k0v), (u16*)&ls[slot_][(512 + tid) * 8]); \
      glds16(Bw + bOff[0] + (k0v), (u16*)&ls[slot_][(1024 + tid) * 8]); \
      glds16(Bw + bOff[1] + (k0v), (u16*)&ls[slot_][(1536 + tid) * 8]); \
      glds16(Bw + bOff[2] + (k0v), (u16*)&ls[slot_][(2048 + tid) * 8]); \
      glds16(Bw + bOff[3] + (k0v), (u16*)&ls[slot_][(2560 + tid) * 8]); \
    } while (0)

    ST3(0, K0G(0));
    asm volatile("s_waitcnt vmcnt(0)" ::: "memory");
    __builtin_amdgcn_sched_barrier(0);
    __builtin_amdgcn_s_barrier();
    __builtin_amdgcn_sched_barrier(0);

#pragma unroll 1
    for (int i = 0; i < nte; ++i) {
      const int s = i & 1, o = s ^ 1;
      const u16* sA = &ls[s][0];
      const u16* sB = &ls[s][8192];
      const bool g1 = (i + 1 < nte);
      short8 af[4], bfv[4];

      if (g1) ST3(o, K0G(i + 1));

      // phase 0: ks0
#pragma unroll
      for (int mi = 0; mi < 4; ++mi) {
        int row = wm * 64 + mi * 16 + l15;
        af[mi] = *(const short8*)&sA[(row * 8 + (lhi ^ (row & 7))) * 8];
      }
#pragma unroll
      for (int ni = 0; ni < 4; ++ni) {
        int row = wn * 64 + ni * 16 + l15;
        bfv[ni] = *(const short8*)&sB[(row * 8 + (lhi ^ (row & 7))) * 8];
      }
      asm volatile("s_waitcnt lgkmcnt(0)" ::: "memory");
      __builtin_amdgcn_sched_barrier(0);
      __builtin_amdgcn_s_setprio(1);
#pragma unroll
      for (int mi = 0; mi < 4; ++mi)
#pragma unroll
        for (int ni = 0; ni < 4; ++ni)
          acc[mi][ni] = __builtin_amdgcn_mfma_f32_16x16x32_bf16(af[mi], bfv[ni], acc[mi][ni], 0, 0, 0);
      __builtin_amdgcn_s_setprio(0);

      // phase 1: ks1
#pragma unroll
      for (int mi = 0; mi < 4; ++mi) {
        int row = wm * 64 + mi * 16 + l15;
        af[mi] = *(const short8*)&sA[(row * 8 + ((4 + lhi) ^ (row & 7))) * 8];
      }
#pragma unroll
      for (int ni = 0; ni < 4; ++ni) {
        int row = wn * 64 + ni * 16 + l15;
        bfv[ni] = *(const short8*)&sB[(row * 8 + ((4 + lhi) ^ (row & 7))) * 8];
      }
      asm volatile("s_waitcnt lgkmcnt(0)" ::: "memory");
      __builtin_amdgcn_sched_barrier(0);
      __builtin_amdgcn_s_setprio(1);
#pragma unroll
      for (int mi = 0; mi < 4; ++mi)
#pragma unroll
        for (int ni = 0; ni < 4; ++ni)
          acc[mi][ni] = __builtin_amdgcn_mfma_f32_16x16x32_bf16(af[mi], bfv[ni], acc[mi][ni], 0, 0, 0);
      __builtin_amdgcn_s_setprio(0);

      asm volatile("s_waitcnt vmcnt(0)" ::: "memory");
      __builtin_amdgcn_sched_barrier(0);
      __builtin_amdgcn_s_barrier();
      __builtin_amdgcn_sched_barrier(0);
    }
#undef K0G
#undef ST3

    // ---------- logprob epilogue ----------
#pragma unroll
    for (int mi = 0; mi < 4; ++mi) {
#pragma unroll
      for (int e = 0; e < 4; ++e) {
        int row = brow + wm * 64 + mi * 16 + lhi * 4 + e;
        float partial = 0.0f;
#pragma unroll
        for (int ni = 0; ni < 4; ++ni) {
          int col = bcol + wn * 64 + ni * 16 + l15;
          float l = acc[mi][ni][e] + bias[col];
          float v = bf2f(vbf[(size_t)row * N + col]);
          float sp = fmaxf(l, 0.0f) + __logf(1.0f + __expf(-fabsf(l)));
          partial += v * l - sp;
        }
#pragma unroll
        for (int off = 1; off < 16; off <<= 1)
          partial += __shfl_xor(partial, off, 64);
        if (l15 == 0) atomicAdd(&outp[row], partial);
      }
    }
  }
}

// ---------------- launcher ----------------
extern "C" void kernel_launch(void* const* d_in, const int* in_sizes, int n_in,
                              void* d_out, int out_size, void* d_ws, size_t ws_size,
                              hipStream_t stream) {
  const float* value = (const float*)d_in[0];
  const float* W1 = (const float*)d_in[1];
  const float* b1 = (const float*)d_in[2];
  const float* W2 = (const float*)d_in[3];
  const float* b2 = (const float*)d_in[4];
  const float* W3 = (const float*)d_in[5];
  const float* b3 = (const float*)d_in[6];
  float* out = (float*)d_out;

  char* ws = (char*)d_ws;
  u16* vbf = (u16*)(ws);                        // B*D bf16
  u16* w1m = (u16*)(ws + 33554432ULL);          // H*D bf16
  u16* w2m = (u16*)(ws + 50331648ULL);          // H*H bf16
  u16* w3m = (u16*)(ws + 83886080ULL);          // D*H bf16
  u16* h1  = (u16*)(ws + 100663296ULL);         // B*H bf16
  u16* h2  = (u16*)(ws + 167772160ULL);         // B*H bf16

  hipMemsetAsync(d_out, 0, (size_t)out_size * sizeof(float), stream);

  cvt_value_kernel<<<2048, 256, 0, stream>>>(value, vbf, (BB * DD) / 4);
  mask_cvt_tile<0><<<dim3(DD / 64, HH / 64), 256, 0, stream>>>(W1, w1m, DD);
  mask_cvt_tile<1><<<dim3(HH / 64, HH / 64), 256, 0, stream>>>(W2, w2m, HH);
  mask_cvt_tile<2><<<dim3(HH / 64, DD / 64), 256, 0, stream>>>(W3, w3m, HH);

  gemm256_kernel<1><<<256, 512, 0, stream>>>(vbf, w1m, b1, h1, BB, HH, DD);
  gemm256_kernel<2><<<256, 512, 0, stream>>>(h1, w2m, b2, h2, BB, HH, HH);
  gemm3p_kernel<<<256, 512, 0, stream>>>(h2, w3m, b3, vbf, out, BB, DD, HH);
}